// Round 1
// baseline (919.298 us; speedup 1.0000x reference)
//
#include <hip/hip_runtime.h>
#include <hip/hip_bf16.h>

// Problem constants (fixed by the reference setup)
#define NN 50000
#define EE 800000
#define DIN 128
#define HH 128
#define DOUT 64
#define BN_EPS 1e-5f

static inline size_t align_up(size_t x, size_t a) { return (x + a - 1) & ~(a - 1); }

// ---------------------------------------------------------------------------
// Graph preprocessing kernels
// ---------------------------------------------------------------------------

// Count in-edges per destination node (self-loops handled analytically).
__global__ void cnt_kernel(const int* __restrict__ ei, int* __restrict__ cnt, int E) {
    int e = blockIdx.x * 256 + threadIdx.x;
    if (e < E) {
        int d = ei[E + e];          // dst row of edge_index
        atomicAdd(&cnt[d], 1);
    }
}

// dinv[i] = rsqrt(deg) with deg = cnt + 1 (self loop)
__global__ void dinv_kernel(const int* __restrict__ cnt, float* __restrict__ dinv, int n) {
    int i = blockIdx.x * 256 + threadIdx.x;
    if (i < n) dinv[i] = rsqrtf((float)(cnt[i] + 1));
}

// Single-block exclusive scan over cnt -> off (n up to ~50k). 1024 threads.
__global__ void scan_kernel(const int* __restrict__ cnt, int* __restrict__ off, int n) {
    __shared__ int wsum[16];
    __shared__ int chunk_carry;
    int tid = threadIdx.x;
    int lane = tid & 63;
    int wid = tid >> 6;
    if (tid == 0) chunk_carry = 0;
    __syncthreads();
    for (int base = 0; base < n; base += 1024) {
        int i = base + tid;
        int v = (i < n) ? cnt[i] : 0;
        int x = v;
        #pragma unroll
        for (int s = 1; s < 64; s <<= 1) {
            int t = __shfl_up(x, s);
            if (lane >= s) x += t;
        }
        if (lane == 63) wsum[wid] = x;
        __syncthreads();
        int carry = chunk_carry;
        int wpre = 0;
        for (int w = 0; w < wid; ++w) wpre += wsum[w];
        if (i < n) off[i] = carry + wpre + x - v;   // exclusive
        __syncthreads();
        if (tid == 0) {
            int tot = 0;
            for (int w = 0; w < 16; ++w) tot += wsum[w];
            chunk_carry = carry + tot;
        }
        __syncthreads();
    }
    if (tid == 0) off[n] = chunk_carry;
}

// Scatter edges into CSR by destination.
__global__ void fill_kernel(const int* __restrict__ ei, const int* __restrict__ off,
                            int* __restrict__ cursor, int* __restrict__ csr_src, int E) {
    int e = blockIdx.x * 256 + threadIdx.x;
    if (e < E) {
        int s = ei[e];
        int d = ei[E + e];
        int pos = off[d] + atomicAdd(&cursor[d], 1);
        csr_src[pos] = s;
    }
}

// ---------------------------------------------------------------------------
// Dense GEMM: Y[n,FOUT] = act(X[n,128] @ W[128,FOUT] + bias)
// Block 256 threads, per-thread 4x4 tile, K chunked by 64 through LDS.
// ---------------------------------------------------------------------------
template <int FOUT, bool RELU, bool BIAS>
__global__ __launch_bounds__(256) void gemm_kernel(const float* __restrict__ X,
                                                   const float* __restrict__ W,
                                                   const float* __restrict__ bias,
                                                   float* __restrict__ Y, int n) {
    constexpr int TC = FOUT / 4;   // threads along cols (each does 4 cols)
    constexpr int TR = 256 / TC;   // threads along rows
    constexpr int BM = TR * 4;     // rows per block

    __shared__ float Wl[64 * FOUT];
    __shared__ float Xl[BM * 64];

    const int row0 = blockIdx.x * BM;
    const int tc = threadIdx.x % TC;
    const int tr = threadIdx.x / TC;

    float acc[4][4] = {};

    for (int kk = 0; kk < 128; kk += 64) {
        // load W chunk rows [kk, kk+64)
        for (int idx = threadIdx.x; idx < 64 * FOUT / 4; idx += 256)
            ((float4*)Wl)[idx] = ((const float4*)(W + (size_t)kk * FOUT))[idx];
        // load X tile: rows [row0, row0+BM), cols [kk, kk+64)
        for (int idx = threadIdx.x; idx < BM * 16; idx += 256) {
            int r = idx / 16, c = idx % 16;
            int gr = row0 + r;
            float4 v = make_float4(0.f, 0.f, 0.f, 0.f);
            if (gr < n) v = ((const float4*)(X + (size_t)gr * 128 + kk))[c];
            ((float4*)Xl)[idx] = v;
        }
        __syncthreads();

        #pragma unroll 8
        for (int k = 0; k < 64; ++k) {
            float4 wv = ((const float4*)(Wl + k * FOUT))[tc];
            #pragma unroll
            for (int i = 0; i < 4; ++i) {
                float xv = Xl[(tr * 4 + i) * 64 + k];
                acc[i][0] += xv * wv.x;
                acc[i][1] += xv * wv.y;
                acc[i][2] += xv * wv.z;
                acc[i][3] += xv * wv.w;
            }
        }
        __syncthreads();
    }

    float4 bv = make_float4(0.f, 0.f, 0.f, 0.f);
    if (BIAS) bv = ((const float4*)bias)[tc];
    #pragma unroll
    for (int i = 0; i < 4; ++i) {
        int gr = row0 + tr * 4 + i;
        if (gr < n) {
            float4 o = make_float4(acc[i][0] + bv.x, acc[i][1] + bv.y,
                                   acc[i][2] + bv.z, acc[i][3] + bv.w);
            if (RELU) {
                o.x = fmaxf(o.x, 0.f); o.y = fmaxf(o.y, 0.f);
                o.z = fmaxf(o.z, 0.f); o.w = fmaxf(o.w, 0.f);
            }
            ((float4*)(Y + (size_t)gr * FOUT))[tc] = o;
        }
    }
}

// ---------------------------------------------------------------------------
// Aggregation: out[i] = sum_{e: dst=i} h[src_e]*dinv[src]*dinv[i]
//                      + h[i]*dinv[i]^2 + bias
// One wave (64 lanes) per node; each lane owns 2 features (float2).
// ---------------------------------------------------------------------------
__global__ __launch_bounds__(256) void agg_kernel(const float* __restrict__ h,
                                                  const float* __restrict__ dinv,
                                                  const int* __restrict__ off,
                                                  const int* __restrict__ csr_src,
                                                  const float* __restrict__ bias,
                                                  float* __restrict__ out, int n) {
    int gwave = (blockIdx.x * blockDim.x + threadIdx.x) >> 6;
    int lane = threadIdx.x & 63;
    int nwaves = (gridDim.x * blockDim.x) >> 6;
    for (int i = gwave; i < n; i += nwaves) {
        float di = dinv[i];
        float2 acc = ((const float2*)(h + (size_t)i * 128))[lane];
        float sw = di * di;
        acc.x *= sw; acc.y *= sw;
        int s0 = off[i], s1 = off[i + 1];
        for (int j = s0; j < s1; ++j) {
            int s = csr_src[j];
            float w = dinv[s] * di;
            float2 hv = ((const float2*)(h + (size_t)s * 128))[lane];
            acc.x += hv.x * w;
            acc.y += hv.y * w;
        }
        float2 b2 = ((const float2*)bias)[lane];
        acc.x += b2.x; acc.y += b2.y;
        ((float2*)(out + (size_t)i * 128))[lane] = acc;
    }
}

// ---------------------------------------------------------------------------
// BatchNorm statistics: per-feature sum and sum-of-squares over N rows.
// ---------------------------------------------------------------------------
__global__ __launch_bounds__(256) void bn_stats_kernel(const float* __restrict__ x,
                                                       float* __restrict__ sums,
                                                       float* __restrict__ sumsq, int n) {
    int f = threadIdx.x & 127;
    int half = threadIdx.x >> 7;   // 0 or 1
    float s = 0.f, q = 0.f;
    for (int r = blockIdx.x * 2 + half; r < n; r += gridDim.x * 2) {
        float v = x[(size_t)r * 128 + f];
        s += v;
        q += v * v;
    }
    atomicAdd(&sums[f], s);
    atomicAdd(&sumsq[f], q);
}

// Fused BN normalize + affine + ReLU (float4 over all N*128 elements)
__global__ __launch_bounds__(256) void bn_apply_kernel(const float* __restrict__ x,
                                                       const float* __restrict__ sums,
                                                       const float* __restrict__ sumsq,
                                                       const float* __restrict__ g,
                                                       const float* __restrict__ b,
                                                       float* __restrict__ y, int n) {
    int idx = blockIdx.x * 256 + threadIdx.x;
    int total = n * 32;   // float4 count
    if (idx >= total) return;
    int c4 = idx & 31;
    float4 v = ((const float4*)x)[idx];
    float4 sm = ((const float4*)sums)[c4];
    float4 sq = ((const float4*)sumsq)[c4];
    float4 gg = ((const float4*)g)[c4];
    float4 bb = ((const float4*)b)[c4];
    const float inv_n = 1.0f / (float)NN;
    float m, var, o;
    float4 out;
    m = sm.x * inv_n; var = sq.x * inv_n - m * m;
    o = (v.x - m) * rsqrtf(var + BN_EPS) * gg.x + bb.x; out.x = fmaxf(o, 0.f);
    m = sm.y * inv_n; var = sq.y * inv_n - m * m;
    o = (v.y - m) * rsqrtf(var + BN_EPS) * gg.y + bb.y; out.y = fmaxf(o, 0.f);
    m = sm.z * inv_n; var = sq.z * inv_n - m * m;
    o = (v.z - m) * rsqrtf(var + BN_EPS) * gg.z + bb.z; out.z = fmaxf(o, 0.f);
    m = sm.w * inv_n; var = sq.w * inv_n - m * m;
    o = (v.w - m) * rsqrtf(var + BN_EPS) * gg.w + bb.w; out.w = fmaxf(o, 0.f);
    ((float4*)y)[idx] = out;
}

// ---------------------------------------------------------------------------
extern "C" void kernel_launch(void* const* d_in, const int* in_sizes, int n_in,
                              void* d_out, int out_size, void* d_ws, size_t ws_size,
                              hipStream_t stream) {
    const float* x        = (const float*)d_in[0];
    const int*   ei       = (const int*)d_in[1];
    const float* pre_w1   = (const float*)d_in[2];
    const float* pre_b1   = (const float*)d_in[3];
    const float* pre_w2   = (const float*)d_in[4];
    const float* pre_b2   = (const float*)d_in[5];
    const float* conv_w0  = (const float*)d_in[6];
    const float* conv_b0  = (const float*)d_in[7];
    const float* conv_w1  = (const float*)d_in[8];
    const float* conv_b1  = (const float*)d_in[9];
    const float* conv_w2  = (const float*)d_in[10];
    const float* conv_b2  = (const float*)d_in[11];
    const float* bn_g0    = (const float*)d_in[12];
    const float* bn_b0    = (const float*)d_in[13];
    const float* bn_g1    = (const float*)d_in[14];
    const float* bn_b1    = (const float*)d_in[15];
    const float* post_w1  = (const float*)d_in[16];
    const float* post_b1  = (const float*)d_in[17];
    const float* post_w2  = (const float*)d_in[18];
    const float* post_b2  = (const float*)d_in[19];
    float* out = (float*)d_out;

    const int n = NN, E = EE;

    // Workspace layout
    char* w = (char*)d_ws;
    int* cnt    = (int*)w;   w += align_up((size_t)n * 4, 512);
    int* off    = (int*)w;   w += align_up((size_t)(n + 1) * 4, 512);
    int* cursor = (int*)w;   w += align_up((size_t)n * 4, 512);
    float* dinv = (float*)w; w += align_up((size_t)n * 4, 512);
    int* csr    = (int*)w;   w += align_up((size_t)E * 4, 512);
    float* bns0 = (float*)w; // sums0
    float* bnq0 = bns0 + 128;
    float* bns1 = bns0 + 256;
    float* bnq1 = bns0 + 384;
    w += align_up(4 * 128 * 4, 512);
    float* A = (float*)w; w += align_up((size_t)n * 128 * 4, 512);
    float* B = (float*)w; w += align_up((size_t)n * 128 * 4, 512);
    float* C = (float*)w; w += align_up((size_t)n * 128 * 4, 512);

    // Zero the buffers that need it
    hipMemsetAsync(cnt, 0, (size_t)n * 4, stream);
    hipMemsetAsync(cursor, 0, (size_t)n * 4, stream);
    hipMemsetAsync(bns0, 0, 4 * 128 * 4, stream);

    // Graph preprocessing: CSR by destination + dinv
    cnt_kernel<<<(E + 255) / 256, 256, 0, stream>>>(ei, cnt, E);
    dinv_kernel<<<(n + 255) / 256, 256, 0, stream>>>(cnt, dinv, n);
    scan_kernel<<<1, 1024, 0, stream>>>(cnt, off, n);
    fill_kernel<<<(E + 255) / 256, 256, 0, stream>>>(ei, off, cursor, csr, E);

    const int gb128 = (n + 31) / 32;    // BM=32 for FOUT=128
    const int gb64  = (n + 63) / 64;    // BM=64 for FOUT=64
    const int agg_blocks = 1024;
    const int bn_stat_blocks = 512;
    const int bn_apply_blocks = (n * 32 + 255) / 256;

    // pre-proc MLP
    gemm_kernel<128, true, true><<<gb128, 256, 0, stream>>>(x, pre_w1, pre_b1, A, n);
    gemm_kernel<128, true, true><<<gb128, 256, 0, stream>>>(A, pre_w2, pre_b2, B, n);

    // conv0 -> BN0 -> relu
    gemm_kernel<128, false, false><<<gb128, 256, 0, stream>>>(B, conv_w0, nullptr, C, n);
    agg_kernel<<<agg_blocks, 256, 0, stream>>>(C, dinv, off, csr, conv_b0, A, n);
    bn_stats_kernel<<<bn_stat_blocks, 256, 0, stream>>>(A, bns0, bnq0, n);
    bn_apply_kernel<<<bn_apply_blocks, 256, 0, stream>>>(A, bns0, bnq0, bn_g0, bn_b0, B, n);

    // conv1 -> BN1 -> relu
    gemm_kernel<128, false, false><<<gb128, 256, 0, stream>>>(B, conv_w1, nullptr, C, n);
    agg_kernel<<<agg_blocks, 256, 0, stream>>>(C, dinv, off, csr, conv_b1, A, n);
    bn_stats_kernel<<<bn_stat_blocks, 256, 0, stream>>>(A, bns1, bnq1, n);
    bn_apply_kernel<<<bn_apply_blocks, 256, 0, stream>>>(A, bns1, bnq1, bn_g1, bn_b1, B, n);

    // conv2 (no BN/relu)
    gemm_kernel<128, false, false><<<gb128, 256, 0, stream>>>(B, conv_w2, nullptr, C, n);
    agg_kernel<<<agg_blocks, 256, 0, stream>>>(C, dinv, off, csr, conv_b2, A, n);

    // post-proc MLP
    gemm_kernel<128, true, true><<<gb128, 256, 0, stream>>>(A, post_w1, post_b1, B, n);
    gemm_kernel<64, false, true><<<gb64, 256, 0, stream>>>(B, post_w2, post_b2, out, n);
}

// Round 2
// 700.981 us; speedup vs baseline: 1.3114x; 1.3114x over previous
//
#include <hip/hip_runtime.h>
#include <hip/hip_bf16.h>

// Problem constants (fixed by the reference setup)
#define NN 50000
#define EE 800000
#define DIN 128
#define HH 128
#define DOUT 64
#define BN_EPS 1e-5f

static inline size_t align_up(size_t x, size_t a) { return (x + a - 1) & ~(a - 1); }

// ---------------------------------------------------------------------------
// Graph preprocessing kernels
// ---------------------------------------------------------------------------

// Count in-edges per destination node (self-loops handled analytically).
__global__ void cnt_kernel(const int* __restrict__ ei, int* __restrict__ cnt, int E) {
    int e = blockIdx.x * 256 + threadIdx.x;
    if (e < E) {
        int d = ei[E + e];          // dst row of edge_index
        atomicAdd(&cnt[d], 1);
    }
}

// dinv[i] = rsqrt(deg) with deg = cnt + 1 (self loop)
__global__ void dinv_kernel(const int* __restrict__ cnt, float* __restrict__ dinv, int n) {
    int i = blockIdx.x * 256 + threadIdx.x;
    if (i < n) dinv[i] = rsqrtf((float)(cnt[i] + 1));
}

// Single-block exclusive scan over cnt -> off (n up to ~50k). 1024 threads.
__global__ void scan_kernel(const int* __restrict__ cnt, int* __restrict__ off, int n) {
    __shared__ int wsum[16];
    __shared__ int chunk_carry;
    int tid = threadIdx.x;
    int lane = tid & 63;
    int wid = tid >> 6;
    if (tid == 0) chunk_carry = 0;
    __syncthreads();
    for (int base = 0; base < n; base += 1024) {
        int i = base + tid;
        int v = (i < n) ? cnt[i] : 0;
        int x = v;
        #pragma unroll
        for (int s = 1; s < 64; s <<= 1) {
            int t = __shfl_up(x, s);
            if (lane >= s) x += t;
        }
        if (lane == 63) wsum[wid] = x;
        __syncthreads();
        int carry = chunk_carry;
        int wpre = 0;
        for (int w = 0; w < wid; ++w) wpre += wsum[w];
        if (i < n) off[i] = carry + wpre + x - v;   // exclusive
        __syncthreads();
        if (tid == 0) {
            int tot = 0;
            for (int w = 0; w < 16; ++w) tot += wsum[w];
            chunk_carry = carry + tot;
        }
        __syncthreads();
    }
    if (tid == 0) off[n] = chunk_carry;
}

// Scatter edges into CSR by destination; also precompute per-edge weight
// w = dinv[src]*dinv[dst] so the hot aggregation loop has one less
// dependent load (index -> dinv gather chain removed).
__global__ void fill_kernel(const int* __restrict__ ei, const int* __restrict__ off,
                            int* __restrict__ cursor, int* __restrict__ csr_src,
                            float* __restrict__ csr_w, const float* __restrict__ dinv,
                            int E) {
    int e = blockIdx.x * 256 + threadIdx.x;
    if (e < E) {
        int s = ei[e];
        int d = ei[E + e];
        int pos = off[d] + atomicAdd(&cursor[d], 1);
        csr_src[pos] = s;
        csr_w[pos] = dinv[s] * dinv[d];
    }
}

// ---------------------------------------------------------------------------
// Dense GEMM: Y[n,FOUT] = act(X[n,128] @ W[128,FOUT] + bias)
// Block 256 threads, per-thread 4x4 tile, K chunked by 64 through LDS.
// ---------------------------------------------------------------------------
template <int FOUT, bool RELU, bool BIAS>
__global__ __launch_bounds__(256) void gemm_kernel(const float* __restrict__ X,
                                                   const float* __restrict__ W,
                                                   const float* __restrict__ bias,
                                                   float* __restrict__ Y, int n) {
    constexpr int TC = FOUT / 4;   // threads along cols (each does 4 cols)
    constexpr int TR = 256 / TC;   // threads along rows
    constexpr int BM = TR * 4;     // rows per block

    __shared__ float Wl[64 * FOUT];
    __shared__ float Xl[BM * 64];

    const int row0 = blockIdx.x * BM;
    const int tc = threadIdx.x % TC;
    const int tr = threadIdx.x / TC;

    float acc[4][4] = {};

    for (int kk = 0; kk < 128; kk += 64) {
        // load W chunk rows [kk, kk+64)
        for (int idx = threadIdx.x; idx < 64 * FOUT / 4; idx += 256)
            ((float4*)Wl)[idx] = ((const float4*)(W + (size_t)kk * FOUT))[idx];
        // load X tile: rows [row0, row0+BM), cols [kk, kk+64)
        for (int idx = threadIdx.x; idx < BM * 16; idx += 256) {
            int r = idx / 16, c = idx % 16;
            int gr = row0 + r;
            float4 v = make_float4(0.f, 0.f, 0.f, 0.f);
            if (gr < n) v = ((const float4*)(X + (size_t)gr * 128 + kk))[c];
            ((float4*)Xl)[idx] = v;
        }
        __syncthreads();

        #pragma unroll 8
        for (int k = 0; k < 64; ++k) {
            float4 wv = ((const float4*)(Wl + k * FOUT))[tc];
            #pragma unroll
            for (int i = 0; i < 4; ++i) {
                float xv = Xl[(tr * 4 + i) * 64 + k];
                acc[i][0] += xv * wv.x;
                acc[i][1] += xv * wv.y;
                acc[i][2] += xv * wv.z;
                acc[i][3] += xv * wv.w;
            }
        }
        __syncthreads();
    }

    float4 bv = make_float4(0.f, 0.f, 0.f, 0.f);
    if (BIAS) bv = ((const float4*)bias)[tc];
    #pragma unroll
    for (int i = 0; i < 4; ++i) {
        int gr = row0 + tr * 4 + i;
        if (gr < n) {
            float4 o = make_float4(acc[i][0] + bv.x, acc[i][1] + bv.y,
                                   acc[i][2] + bv.z, acc[i][3] + bv.w);
            if (RELU) {
                o.x = fmaxf(o.x, 0.f); o.y = fmaxf(o.y, 0.f);
                o.z = fmaxf(o.z, 0.f); o.w = fmaxf(o.w, 0.f);
            }
            ((float4*)(Y + (size_t)gr * FOUT))[tc] = o;
        }
    }
}

// ---------------------------------------------------------------------------
// Aggregation: out[i] = sum_{e: dst=i} h[src_e]*w_e + h[i]*dinv[i]^2 + bias
// One wave (64 lanes) per node, exactly; lane owns 2 features (float2).
// Edge loop unrolled x4 for memory-level parallelism.
// ---------------------------------------------------------------------------
__global__ __launch_bounds__(256) void agg_kernel(const float* __restrict__ h,
                                                  const float* __restrict__ dinv,
                                                  const int* __restrict__ off,
                                                  const int* __restrict__ csr_src,
                                                  const float* __restrict__ csr_w,
                                                  const float* __restrict__ bias,
                                                  float* __restrict__ out, int n) {
    int i = (blockIdx.x * 256 + threadIdx.x) >> 6;
    if (i >= n) return;
    int lane = threadIdx.x & 63;

    float di = dinv[i];
    float2 acc = ((const float2*)(h + (size_t)i * 128))[lane];
    float sw = di * di;
    acc.x *= sw; acc.y *= sw;

    const int s0 = off[i], s1 = off[i + 1];
    int j = s0;
    for (; j + 4 <= s1; j += 4) {
        int sa = csr_src[j + 0], sb = csr_src[j + 1];
        int sc = csr_src[j + 2], sd = csr_src[j + 3];
        float wa = csr_w[j + 0], wb = csr_w[j + 1];
        float wc = csr_w[j + 2], wd = csr_w[j + 3];
        float2 ha = ((const float2*)(h + (size_t)sa * 128))[lane];
        float2 hb = ((const float2*)(h + (size_t)sb * 128))[lane];
        float2 hc = ((const float2*)(h + (size_t)sc * 128))[lane];
        float2 hd = ((const float2*)(h + (size_t)sd * 128))[lane];
        acc.x += ha.x * wa + hb.x * wb + hc.x * wc + hd.x * wd;
        acc.y += ha.y * wa + hb.y * wb + hc.y * wc + hd.y * wd;
    }
    for (; j < s1; ++j) {
        int s = csr_src[j];
        float w = csr_w[j];
        float2 hv = ((const float2*)(h + (size_t)s * 128))[lane];
        acc.x += hv.x * w;
        acc.y += hv.y * w;
    }

    float2 b2 = ((const float2*)bias)[lane];
    acc.x += b2.x; acc.y += b2.y;
    ((float2*)(out + (size_t)i * 128))[lane] = acc;
}

// ---------------------------------------------------------------------------
// BatchNorm statistics: per-feature sum and sum-of-squares over N rows.
// ---------------------------------------------------------------------------
__global__ __launch_bounds__(256) void bn_stats_kernel(const float* __restrict__ x,
                                                       float* __restrict__ sums,
                                                       float* __restrict__ sumsq, int n) {
    int f = threadIdx.x & 127;
    int half = threadIdx.x >> 7;   // 0 or 1
    float s = 0.f, q = 0.f;
    for (int r = blockIdx.x * 2 + half; r < n; r += gridDim.x * 2) {
        float v = x[(size_t)r * 128 + f];
        s += v;
        q += v * v;
    }
    atomicAdd(&sums[f], s);
    atomicAdd(&sumsq[f], q);
}

// Fused BN normalize + affine + ReLU (float4 over all N*128 elements)
__global__ __launch_bounds__(256) void bn_apply_kernel(const float* __restrict__ x,
                                                       const float* __restrict__ sums,
                                                       const float* __restrict__ sumsq,
                                                       const float* __restrict__ g,
                                                       const float* __restrict__ b,
                                                       float* __restrict__ y, int n) {
    int idx = blockIdx.x * 256 + threadIdx.x;
    int total = n * 32;   // float4 count
    if (idx >= total) return;
    int c4 = idx & 31;
    float4 v = ((const float4*)x)[idx];
    float4 sm = ((const float4*)sums)[c4];
    float4 sq = ((const float4*)sumsq)[c4];
    float4 gg = ((const float4*)g)[c4];
    float4 bb = ((const float4*)b)[c4];
    const float inv_n = 1.0f / (float)NN;
    float m, var, o;
    float4 out;
    m = sm.x * inv_n; var = sq.x * inv_n - m * m;
    o = (v.x - m) * rsqrtf(var + BN_EPS) * gg.x + bb.x; out.x = fmaxf(o, 0.f);
    m = sm.y * inv_n; var = sq.y * inv_n - m * m;
    o = (v.y - m) * rsqrtf(var + BN_EPS) * gg.y + bb.y; out.y = fmaxf(o, 0.f);
    m = sm.z * inv_n; var = sq.z * inv_n - m * m;
    o = (v.z - m) * rsqrtf(var + BN_EPS) * gg.z + bb.z; out.z = fmaxf(o, 0.f);
    m = sm.w * inv_n; var = sq.w * inv_n - m * m;
    o = (v.w - m) * rsqrtf(var + BN_EPS) * gg.w + bb.w; out.w = fmaxf(o, 0.f);
    ((float4*)y)[idx] = out;
}

// ---------------------------------------------------------------------------
extern "C" void kernel_launch(void* const* d_in, const int* in_sizes, int n_in,
                              void* d_out, int out_size, void* d_ws, size_t ws_size,
                              hipStream_t stream) {
    const float* x        = (const float*)d_in[0];
    const int*   ei       = (const int*)d_in[1];
    const float* pre_w1   = (const float*)d_in[2];
    const float* pre_b1   = (const float*)d_in[3];
    const float* pre_w2   = (const float*)d_in[4];
    const float* pre_b2   = (const float*)d_in[5];
    const float* conv_w0  = (const float*)d_in[6];
    const float* conv_b0  = (const float*)d_in[7];
    const float* conv_w1  = (const float*)d_in[8];
    const float* conv_b1  = (const float*)d_in[9];
    const float* conv_w2  = (const float*)d_in[10];
    const float* conv_b2  = (const float*)d_in[11];
    const float* bn_g0    = (const float*)d_in[12];
    const float* bn_b0    = (const float*)d_in[13];
    const float* bn_g1    = (const float*)d_in[14];
    const float* bn_b1    = (const float*)d_in[15];
    const float* post_w1  = (const float*)d_in[16];
    const float* post_b1  = (const float*)d_in[17];
    const float* post_w2  = (const float*)d_in[18];
    const float* post_b2  = (const float*)d_in[19];
    float* out = (float*)d_out;

    const int n = NN, E = EE;

    // Workspace layout
    char* w = (char*)d_ws;
    int* cnt    = (int*)w;   w += align_up((size_t)n * 4, 512);
    int* off    = (int*)w;   w += align_up((size_t)(n + 1) * 4, 512);
    int* cursor = (int*)w;   w += align_up((size_t)n * 4, 512);
    float* dinv = (float*)w; w += align_up((size_t)n * 4, 512);
    int* csr    = (int*)w;   w += align_up((size_t)E * 4, 512);
    float* csrw = (float*)w; w += align_up((size_t)E * 4, 512);
    float* bns0 = (float*)w; // sums0
    float* bnq0 = bns0 + 128;
    float* bns1 = bns0 + 256;
    float* bnq1 = bns0 + 384;
    w += align_up(4 * 128 * 4, 512);
    float* A = (float*)w; w += align_up((size_t)n * 128 * 4, 512);
    float* B = (float*)w; w += align_up((size_t)n * 128 * 4, 512);
    float* C = (float*)w; w += align_up((size_t)n * 128 * 4, 512);

    // Zero the buffers that need it
    hipMemsetAsync(cnt, 0, (size_t)n * 4, stream);
    hipMemsetAsync(cursor, 0, (size_t)n * 4, stream);
    hipMemsetAsync(bns0, 0, 4 * 128 * 4, stream);

    // Graph preprocessing: CSR by destination + dinv + per-edge weights
    cnt_kernel<<<(E + 255) / 256, 256, 0, stream>>>(ei, cnt, E);
    dinv_kernel<<<(n + 255) / 256, 256, 0, stream>>>(cnt, dinv, n);
    scan_kernel<<<1, 1024, 0, stream>>>(cnt, off, n);
    fill_kernel<<<(E + 255) / 256, 256, 0, stream>>>(ei, off, cursor, csr, csrw, dinv, E);

    const int gb128 = (n + 31) / 32;    // BM=32 for FOUT=128
    const int gb64  = (n + 63) / 64;    // BM=64 for FOUT=64
    const int agg_blocks = (n * 64 + 255) / 256;   // one wave per node
    const int bn_stat_blocks = 512;
    const int bn_apply_blocks = (n * 32 + 255) / 256;

    // pre-proc MLP
    gemm_kernel<128, true, true><<<gb128, 256, 0, stream>>>(x, pre_w1, pre_b1, A, n);
    gemm_kernel<128, true, true><<<gb128, 256, 0, stream>>>(A, pre_w2, pre_b2, B, n);

    // conv0 -> BN0 -> relu
    gemm_kernel<128, false, false><<<gb128, 256, 0, stream>>>(B, conv_w0, nullptr, C, n);
    agg_kernel<<<agg_blocks, 256, 0, stream>>>(C, dinv, off, csr, csrw, conv_b0, A, n);
    bn_stats_kernel<<<bn_stat_blocks, 256, 0, stream>>>(A, bns0, bnq0, n);
    bn_apply_kernel<<<bn_apply_blocks, 256, 0, stream>>>(A, bns0, bnq0, bn_g0, bn_b0, B, n);

    // conv1 -> BN1 -> relu
    gemm_kernel<128, false, false><<<gb128, 256, 0, stream>>>(B, conv_w1, nullptr, C, n);
    agg_kernel<<<agg_blocks, 256, 0, stream>>>(C, dinv, off, csr, csrw, conv_b1, A, n);
    bn_stats_kernel<<<bn_stat_blocks, 256, 0, stream>>>(A, bns1, bnq1, n);
    bn_apply_kernel<<<bn_apply_blocks, 256, 0, stream>>>(A, bns1, bnq1, bn_g1, bn_b1, B, n);

    // conv2 (no BN/relu)
    gemm_kernel<128, false, false><<<gb128, 256, 0, stream>>>(B, conv_w2, nullptr, C, n);
    agg_kernel<<<agg_blocks, 256, 0, stream>>>(C, dinv, off, csr, csrw, conv_b2, A, n);

    // post-proc MLP
    gemm_kernel<128, true, true><<<gb128, 256, 0, stream>>>(A, post_w1, post_b1, B, n);
    gemm_kernel<64, false, true><<<gb64, 256, 0, stream>>>(B, post_w2, post_b2, out, n);
}

// Round 3
// 500.973 us; speedup vs baseline: 1.8350x; 1.3992x over previous
//
#include <hip/hip_runtime.h>
#include <hip/hip_bf16.h>

// Problem constants (fixed by the reference setup)
#define NN 50000
#define EE 800000
#define DIN 128
#define HH 128
#define DOUT 64
#define BN_EPS 1e-5f

typedef __attribute__((ext_vector_type(8))) short short8;   // 8 bf16 (4 VGPRs)
typedef __attribute__((ext_vector_type(4))) float floatx4;  // MFMA acc

static inline size_t align_up(size_t x, size_t a) { return (x + a - 1) & ~(a - 1); }

// bf16 <-> f32 helpers (RNE round)
__device__ __forceinline__ float bf2f(ushort u) {
    uint v = ((uint)u) << 16;
    return __builtin_bit_cast(float, v);
}
__device__ __forceinline__ float bf2f_lo(uint u) { return __builtin_bit_cast(float, u << 16); }
__device__ __forceinline__ float bf2f_hi(uint u) { return __builtin_bit_cast(float, u & 0xffff0000u); }
__device__ __forceinline__ ushort f2bf(float f) {
    uint u = __builtin_bit_cast(uint, f);
    u += 0x7fff + ((u >> 16) & 1);
    return (ushort)(u >> 16);
}

// ---------------------------------------------------------------------------
// Casts
// ---------------------------------------------------------------------------
__global__ void castx_kernel(const float* __restrict__ src, ushort* __restrict__ dst, int total4) {
    int t = blockIdx.x * 256 + threadIdx.x;
    if (t >= total4) return;
    float4 v = ((const float4*)src)[t];
    ushort4 o;
    o.x = f2bf(v.x); o.y = f2bf(v.y); o.z = f2bf(v.z); o.w = f2bf(v.w);
    ((ushort4*)dst)[t] = o;
}

// W[k][f] f32 (K=128 rows) -> Wt[f][k] bf16 (k contiguous)
__global__ void tcast_kernel(const float* __restrict__ src, ushort* __restrict__ dst, int F) {
    int t = blockIdx.x * 256 + threadIdx.x;
    if (t >= F * 128) return;
    int f = t >> 7, k = t & 127;
    dst[t] = f2bf(src[(size_t)k * F + f]);
}

// ---------------------------------------------------------------------------
// Graph preprocessing
// ---------------------------------------------------------------------------
__global__ void cnt_kernel(const int* __restrict__ ei, int* __restrict__ cnt, int E) {
    int e = blockIdx.x * 256 + threadIdx.x;
    if (e < E) atomicAdd(&cnt[ei[E + e]], 1);
}

__global__ void dinv_kernel(const int* __restrict__ cnt, float* __restrict__ dinv, int n) {
    int i = blockIdx.x * 256 + threadIdx.x;
    if (i < n) dinv[i] = rsqrtf((float)(cnt[i] + 1));
}

// 3-phase scan: per-block exclusive scan + block sums
__device__ __forceinline__ void block_scan256(int v, int* lsum, int& excl, int& total) {
    int lane = threadIdx.x & 63, w = threadIdx.x >> 6;
    int inc = v;
    #pragma unroll
    for (int s = 1; s < 64; s <<= 1) {
        int t = __shfl_up(inc, s);
        if (lane >= s) inc += t;
    }
    if (lane == 63) lsum[w] = inc;
    __syncthreads();
    int pre = 0;
    #pragma unroll
    for (int k = 0; k < 4; ++k)
        if (k < w) pre += lsum[k];
    excl = pre + inc - v;
    total = lsum[0] + lsum[1] + lsum[2] + lsum[3];
    __syncthreads();
}

__global__ void scan_part_kernel(const int* __restrict__ cnt, int* __restrict__ part,
                                 int* __restrict__ bsum, int n) {
    __shared__ int lsum[4];
    int i = blockIdx.x * 256 + threadIdx.x;
    int v = (i < n) ? cnt[i] : 0;
    int excl, total;
    block_scan256(v, lsum, excl, total);
    if (i < n) part[i] = excl;
    if (threadIdx.x == 0) bsum[blockIdx.x] = total;
}

__global__ void scan_bsum_kernel(int* __restrict__ bsum, int nb) {
    __shared__ int lsum[4];
    int t = threadIdx.x;
    int v = (t < nb) ? bsum[t] : 0;
    int excl, total;
    block_scan256(v, lsum, excl, total);
    if (t < nb) bsum[t] = excl;
}

__global__ void scan_add_kernel(const int* __restrict__ part, const int* __restrict__ bsum,
                                int* __restrict__ off, int n) {
    int i = blockIdx.x * 256 + threadIdx.x;
    if (i < n) off[i] = part[i] + bsum[blockIdx.x];
    if (i == 0) off[n] = EE;
}

__global__ void fill_kernel(const int* __restrict__ ei, const int* __restrict__ off,
                            int* __restrict__ cursor, int* __restrict__ csr_src,
                            float* __restrict__ csr_w, const float* __restrict__ dinv,
                            int E) {
    int e = blockIdx.x * 256 + threadIdx.x;
    if (e < E) {
        int s = ei[e];
        int d = ei[E + e];
        int pos = off[d] + atomicAdd(&cursor[d], 1);
        csr_src[pos] = s;
        csr_w[pos] = dinv[s] * dinv[d];
    }
}

// ---------------------------------------------------------------------------
// MFMA GEMM: Y[n,FOUT] = act(X[n,128] @ W[128,FOUT] + bias)
// X: bf16 row-major [n][128]; Wt: bf16 [FOUT][128] (pre-transposed, k contig).
// Block: 128 rows x FOUT cols, 4 waves (each 32 rows). K=128 LDS-resident.
// LDS 16B-chunk layout with XOR swizzle (kb ^= row&15) -> 2-way (free) reads.
// BNF: fold BatchNorm(scale,shift)+ReLU into X staging.
// ---------------------------------------------------------------------------
template <int FOUT, bool RELU, bool BIAS, bool BNF, bool OUTF32>
__global__ __launch_bounds__(256, 2) void gemm_mfma(
    const ushort* __restrict__ Xg, const ushort* __restrict__ Wt,
    const float* __restrict__ bias, const float* __restrict__ scale,
    const float* __restrict__ shift, void* __restrict__ Yout, int n) {
    constexpr int NCG = FOUT / 16;
    __shared__ uint4 lds4[2048 + FOUT * 16];
    uint4* Wl = lds4 + 2048;
    const int tid = threadIdx.x;
    const int row0 = blockIdx.x * 128;

    // stage W (bf16, pre-transposed: coalesced 16B chunks)
    #pragma unroll
    for (int c = tid; c < FOUT * 16; c += 256) {
        int f = c >> 4, kb = c & 15;
        uint4 v = ((const uint4*)Wt)[c];
        Wl[f * 16 + (kb ^ (f & 15))] = v;
    }
    // stage X (optionally with BN+ReLU fold)
    for (int c = tid; c < 2048; c += 256) {
        int r = c >> 4, kb = c & 15;
        int row = row0 + r;
        uint4 v = make_uint4(0, 0, 0, 0);
        if (row < n) v = ((const uint4*)(Xg + (size_t)row * 128))[kb];
        if (BNF) {
            uint a[4] = {v.x, v.y, v.z, v.w};
            #pragma unroll
            for (int p = 0; p < 4; ++p) {
                int f0 = kb * 8 + p * 2;
                float lo = bf2f_lo(a[p]);
                float hi = bf2f_hi(a[p]);
                lo = fmaxf(fmaf(lo, scale[f0], shift[f0]), 0.f);
                hi = fmaxf(fmaf(hi, scale[f0 + 1], shift[f0 + 1]), 0.f);
                a[p] = (uint)f2bf(lo) | ((uint)f2bf(hi) << 16);
            }
            v = make_uint4(a[0], a[1], a[2], a[3]);
        }
        lds4[r * 16 + (kb ^ (r & 15))] = v;
    }
    __syncthreads();

    const int wv = tid >> 6, lane = tid & 63;
    const int lr = lane & 15, lk = lane >> 4;

    floatx4 acc[2][NCG];
    #pragma unroll
    for (int rg = 0; rg < 2; ++rg)
        #pragma unroll
        for (int cg = 0; cg < NCG; ++cg)
            acc[rg][cg] = (floatx4){0.f, 0.f, 0.f, 0.f};

    #pragma unroll
    for (int ks = 0; ks < 4; ++ks) {
        int kb = ks * 4 + lk;          // this lane's 16B chunk along K
        int swz = kb ^ lr;             // same swizzle for A (row&15=lr) and B (f&15=lr)
        short8 a0 = *(const short8*)&lds4[(wv * 32 + lr) * 16 + swz];
        short8 a1 = *(const short8*)&lds4[(wv * 32 + 16 + lr) * 16 + swz];
        #pragma unroll
        for (int cg = 0; cg < NCG; ++cg) {
            short8 b = *(const short8*)&Wl[(cg * 16 + lr) * 16 + swz];
            acc[0][cg] = __builtin_amdgcn_mfma_f32_16x16x32_bf16(a0, b, acc[0][cg], 0, 0, 0);
            acc[1][cg] = __builtin_amdgcn_mfma_f32_16x16x32_bf16(a1, b, acc[1][cg], 0, 0, 0);
        }
    }

    // epilogue: D mapping col=lane&15, row=(lane>>4)*4+j
    #pragma unroll
    for (int rg = 0; rg < 2; ++rg) {
        int rbase = row0 + wv * 32 + rg * 16 + lk * 4;
        #pragma unroll
        for (int cg = 0; cg < NCG; ++cg) {
            int col = cg * 16 + lr;
            float bv = BIAS ? bias[col] : 0.f;
            #pragma unroll
            for (int j = 0; j < 4; ++j) {
                int r = rbase + j;
                if (r < n) {
                    float o = acc[rg][cg][j] + bv;
                    if (RELU) o = fmaxf(o, 0.f);
                    if (OUTF32)
                        ((float*)Yout)[(size_t)r * FOUT + col] = o;
                    else
                        ((ushort*)Yout)[(size_t)r * FOUT + col] = f2bf(o);
                }
            }
        }
    }
}

// ---------------------------------------------------------------------------
// Aggregation (bf16 rows): out[i] = sum_e h[src_e]*w_e + h[i]*dinv^2 + bias
// One wave per node; lane owns 2 features (one dword of 2 bf16). f32 accum.
// ---------------------------------------------------------------------------
__global__ __launch_bounds__(256) void agg16_kernel(const ushort* __restrict__ h,
                                                    const float* __restrict__ dinv,
                                                    const int* __restrict__ off,
                                                    const int* __restrict__ csr_src,
                                                    const float* __restrict__ csr_w,
                                                    const float* __restrict__ bias,
                                                    ushort* __restrict__ out, int n) {
    int i = (blockIdx.x * 256 + threadIdx.x) >> 6;
    if (i >= n) return;
    int lane = threadIdx.x & 63;

    float di = dinv[i];
    float sw = di * di;
    uint u = ((const uint*)(h + (size_t)i * 128))[lane];
    float a0 = bf2f_lo(u) * sw, a1 = bf2f_hi(u) * sw;

    const int s0 = off[i], s1 = off[i + 1];
    int j = s0;
    for (; j + 4 <= s1; j += 4) {
        int sa = csr_src[j + 0], sb = csr_src[j + 1];
        int sc = csr_src[j + 2], sd = csr_src[j + 3];
        float wa = csr_w[j + 0], wb = csr_w[j + 1];
        float wc = csr_w[j + 2], wd = csr_w[j + 3];
        uint ua = ((const uint*)(h + (size_t)sa * 128))[lane];
        uint ub = ((const uint*)(h + (size_t)sb * 128))[lane];
        uint uc = ((const uint*)(h + (size_t)sc * 128))[lane];
        uint ud = ((const uint*)(h + (size_t)sd * 128))[lane];
        a0 += bf2f_lo(ua) * wa + bf2f_lo(ub) * wb + bf2f_lo(uc) * wc + bf2f_lo(ud) * wd;
        a1 += bf2f_hi(ua) * wa + bf2f_hi(ub) * wb + bf2f_hi(uc) * wc + bf2f_hi(ud) * wd;
    }
    for (; j < s1; ++j) {
        int s = csr_src[j];
        float w = csr_w[j];
        uint uv = ((const uint*)(h + (size_t)s * 128))[lane];
        a0 += bf2f_lo(uv) * w;
        a1 += bf2f_hi(uv) * w;
    }

    float2 b2 = ((const float2*)bias)[lane];
    a0 += b2.x; a1 += b2.y;
    uint o = (uint)f2bf(a0) | ((uint)f2bf(a1) << 16);
    ((uint*)(out + (size_t)i * 128))[lane] = o;
}

// ---------------------------------------------------------------------------
// BatchNorm: stats on bf16 rows, then per-feature scale/shift coefficients
// ---------------------------------------------------------------------------
__global__ __launch_bounds__(256) void bn_stats16_kernel(const ushort* __restrict__ x,
                                                         float* __restrict__ sums,
                                                         float* __restrict__ sumsq, int n) {
    int f = threadIdx.x & 127;
    int half = threadIdx.x >> 7;
    float s = 0.f, q = 0.f;
    for (int r = blockIdx.x * 2 + half; r < n; r += gridDim.x * 2) {
        float v = bf2f(x[(size_t)r * 128 + f]);
        s += v;
        q += v * v;
    }
    atomicAdd(&sums[f], s);
    atomicAdd(&sumsq[f], q);
}

__global__ void bn_coef_kernel(const float* __restrict__ sums, const float* __restrict__ sumsq,
                               const float* __restrict__ g, const float* __restrict__ b,
                               float* __restrict__ scale, float* __restrict__ shift) {
    int f = threadIdx.x;
    if (f >= 128) return;
    const float inv_n = 1.0f / (float)NN;
    float m = sums[f] * inv_n;
    float var = sumsq[f] * inv_n - m * m;
    float sc = g[f] * rsqrtf(var + BN_EPS);
    scale[f] = sc;
    shift[f] = b[f] - m * sc;
}

// ---------------------------------------------------------------------------
extern "C" void kernel_launch(void* const* d_in, const int* in_sizes, int n_in,
                              void* d_out, int out_size, void* d_ws, size_t ws_size,
                              hipStream_t stream) {
    const float* x        = (const float*)d_in[0];
    const int*   ei       = (const int*)d_in[1];
    const float* pre_w1   = (const float*)d_in[2];
    const float* pre_b1   = (const float*)d_in[3];
    const float* pre_w2   = (const float*)d_in[4];
    const float* pre_b2   = (const float*)d_in[5];
    const float* conv_w0  = (const float*)d_in[6];
    const float* conv_b0  = (const float*)d_in[7];
    const float* conv_w1  = (const float*)d_in[8];
    const float* conv_b1  = (const float*)d_in[9];
    const float* conv_w2  = (const float*)d_in[10];
    const float* conv_b2  = (const float*)d_in[11];
    const float* bn_g0    = (const float*)d_in[12];
    const float* bn_b0    = (const float*)d_in[13];
    const float* bn_g1    = (const float*)d_in[14];
    const float* bn_b1    = (const float*)d_in[15];
    const float* post_w1  = (const float*)d_in[16];
    const float* post_b1  = (const float*)d_in[17];
    const float* post_w2  = (const float*)d_in[18];
    const float* post_b2  = (const float*)d_in[19];
    float* out = (float*)d_out;

    const int n = NN, E = EE;
    const int NB = (n + 255) / 256;   // scan blocks (196)

    // Workspace layout
    char* w = (char*)d_ws;
    int* cnt    = (int*)w;   w += align_up((size_t)n * 4, 512);
    int* cursor = (int*)w;   w += align_up((size_t)n * 4, 512);
    int* part   = (int*)w;   w += align_up((size_t)n * 4, 512);
    int* bsum   = (int*)w;   w += align_up(256 * 4, 512);
    int* off    = (int*)w;   w += align_up((size_t)(n + 1) * 4, 512);
    float* dinv = (float*)w; w += align_up((size_t)n * 4, 512);
    int* csr    = (int*)w;   w += align_up((size_t)E * 4, 512);
    float* csrw = (float*)w; w += align_up((size_t)E * 4, 512);
    float* bns0 = (float*)w;            // sums0, sumsq0, sums1, sumsq1
    float* bnq0 = bns0 + 128;
    float* bns1 = bns0 + 256;
    float* bnq1 = bns0 + 384;
    w += align_up(4 * 128 * 4, 512);
    float* sc0  = (float*)w;            // scale0, shift0, scale1, shift1
    float* sh0  = sc0 + 128;
    float* sc1  = sc0 + 256;
    float* sh1  = sc0 + 384;
    w += align_up(4 * 128 * 4, 512);
    // bf16 transposed weights
    ushort* wt_pre1  = (ushort*)w; w += align_up(128 * 128 * 2, 512);
    ushort* wt_pre2  = (ushort*)w; w += align_up(128 * 128 * 2, 512);
    ushort* wt_c0    = (ushort*)w; w += align_up(128 * 128 * 2, 512);
    ushort* wt_c1    = (ushort*)w; w += align_up(128 * 128 * 2, 512);
    ushort* wt_c2    = (ushort*)w; w += align_up(128 * 128 * 2, 512);
    ushort* wt_post1 = (ushort*)w; w += align_up(128 * 128 * 2, 512);
    ushort* wt_post2 = (ushort*)w; w += align_up(64 * 128 * 2, 512);
    // bf16 activation buffers
    ushort* P = (ushort*)w; w += align_up((size_t)n * 128 * 2, 512);
    ushort* Q = (ushort*)w; w += align_up((size_t)n * 128 * 2, 512);
    ushort* R = (ushort*)w; w += align_up((size_t)n * 128 * 2, 512);

    hipMemsetAsync(cnt, 0, (size_t)n * 4, stream);
    hipMemsetAsync(cursor, 0, (size_t)n * 4, stream);
    hipMemsetAsync(bns0, 0, 4 * 128 * 4, stream);

    // Casts
    castx_kernel<<<(n * 32 + 255) / 256, 256, 0, stream>>>(x, P, n * 32);
    tcast_kernel<<<64, 256, 0, stream>>>(pre_w1, wt_pre1, 128);
    tcast_kernel<<<64, 256, 0, stream>>>(pre_w2, wt_pre2, 128);
    tcast_kernel<<<64, 256, 0, stream>>>(conv_w0, wt_c0, 128);
    tcast_kernel<<<64, 256, 0, stream>>>(conv_w1, wt_c1, 128);
    tcast_kernel<<<64, 256, 0, stream>>>(conv_w2, wt_c2, 128);
    tcast_kernel<<<64, 256, 0, stream>>>(post_w1, wt_post1, 128);
    tcast_kernel<<<32, 256, 0, stream>>>(post_w2, wt_post2, 64);

    // Graph preprocessing
    cnt_kernel<<<(E + 255) / 256, 256, 0, stream>>>(ei, cnt, E);
    dinv_kernel<<<NB, 256, 0, stream>>>(cnt, dinv, n);
    scan_part_kernel<<<NB, 256, 0, stream>>>(cnt, part, bsum, n);
    scan_bsum_kernel<<<1, 256, 0, stream>>>(bsum, NB);
    scan_add_kernel<<<NB, 256, 0, stream>>>(part, bsum, off, n);
    fill_kernel<<<(E + 255) / 256, 256, 0, stream>>>(ei, off, cursor, csr, csrw, dinv, E);

    const int gb = (n + 127) / 128;
    const int agg_blocks = (n * 64 + 255) / 256;

    // pre-proc MLP
    gemm_mfma<128, true, true, false, false><<<gb, 256, 0, stream>>>(P, wt_pre1, pre_b1, nullptr, nullptr, Q, n);
    gemm_mfma<128, true, true, false, false><<<gb, 256, 0, stream>>>(Q, wt_pre2, pre_b2, nullptr, nullptr, R, n);

    // conv0 -> agg -> BN0 stats/coefs (BN+ReLU folded into conv1 staging)
    gemm_mfma<128, false, false, false, false><<<gb, 256, 0, stream>>>(R, wt_c0, nullptr, nullptr, nullptr, P, n);
    agg16_kernel<<<agg_blocks, 256, 0, stream>>>(P, dinv, off, csr, csrw, conv_b0, Q, n);
    bn_stats16_kernel<<<512, 256, 0, stream>>>(Q, bns0, bnq0, n);
    bn_coef_kernel<<<1, 128, 0, stream>>>(bns0, bnq0, bn_g0, bn_b0, sc0, sh0);

    // conv1 (BN0 fold) -> agg -> BN1 stats/coefs
    gemm_mfma<128, false, false, true, false><<<gb, 256, 0, stream>>>(Q, wt_c1, nullptr, sc0, sh0, P, n);
    agg16_kernel<<<agg_blocks, 256, 0, stream>>>(P, dinv, off, csr, csrw, conv_b1, R, n);
    bn_stats16_kernel<<<512, 256, 0, stream>>>(R, bns1, bnq1, n);
    bn_coef_kernel<<<1, 128, 0, stream>>>(bns1, bnq1, bn_g1, bn_b1, sc1, sh1);

    // conv2 (BN1 fold) -> agg
    gemm_mfma<128, false, false, true, false><<<gb, 256, 0, stream>>>(R, wt_c2, nullptr, sc1, sh1, P, n);
    agg16_kernel<<<agg_blocks, 256, 0, stream>>>(P, dinv, off, csr, csrw, conv_b2, Q, n);

    // post-proc MLP
    gemm_mfma<128, true, true, false, false><<<gb, 256, 0, stream>>>(Q, wt_post1, post_b1, nullptr, nullptr, P, n);
    gemm_mfma<64, false, true, false, true><<<gb, 256, 0, stream>>>(P, wt_post2, post_b2, nullptr, nullptr, out, n);
}

// Round 4
// 489.848 us; speedup vs baseline: 1.8767x; 1.0227x over previous
//
#include <hip/hip_runtime.h>
#include <hip/hip_bf16.h>

// Problem constants (fixed by the reference setup)
#define NN 50000
#define EE 800000
#define DIN 128
#define HH 128
#define DOUT 64
#define BN_EPS 1e-5f

typedef __attribute__((ext_vector_type(8))) short short8;   // 8 bf16 (4 VGPRs)
typedef __attribute__((ext_vector_type(4))) float floatx4;  // MFMA acc

static inline size_t align_up(size_t x, size_t a) { return (x + a - 1) & ~(a - 1); }

// bf16 <-> f32 helpers (RNE round)
__device__ __forceinline__ float bf2f(ushort u) {
    uint v = ((uint)u) << 16;
    return __builtin_bit_cast(float, v);
}
__device__ __forceinline__ float bf2f_lo(uint u) { return __builtin_bit_cast(float, u << 16); }
__device__ __forceinline__ float bf2f_hi(uint u) { return __builtin_bit_cast(float, u & 0xffff0000u); }
__device__ __forceinline__ ushort f2bf(float f) {
    uint u = __builtin_bit_cast(uint, f);
    u += 0x7fff + ((u >> 16) & 1);
    return (ushort)(u >> 16);
}

// ---------------------------------------------------------------------------
// Casts
// ---------------------------------------------------------------------------
__global__ void castx_kernel(const float* __restrict__ src, ushort* __restrict__ dst, int total4) {
    int t = blockIdx.x * 256 + threadIdx.x;
    if (t >= total4) return;
    float4 v = ((const float4*)src)[t];
    ushort4 o;
    o.x = f2bf(v.x); o.y = f2bf(v.y); o.z = f2bf(v.z); o.w = f2bf(v.w);
    ((ushort4*)dst)[t] = o;
}

// All 7 weights in one dispatch: W[k][f] f32 -> Wt[f][k] bf16 (k contiguous)
__global__ void tcast_all_kernel(const float* __restrict__ s0, const float* __restrict__ s1,
                                 const float* __restrict__ s2, const float* __restrict__ s3,
                                 const float* __restrict__ s4, const float* __restrict__ s5,
                                 const float* __restrict__ s6,
                                 ushort* __restrict__ d0, ushort* __restrict__ d1,
                                 ushort* __restrict__ d2, ushort* __restrict__ d3,
                                 ushort* __restrict__ d4, ushort* __restrict__ d5,
                                 ushort* __restrict__ d6) {
    const float* src; ushort* dst; int F = 128;
    switch (blockIdx.y) {
        case 0: src = s0; dst = d0; break;
        case 1: src = s1; dst = d1; break;
        case 2: src = s2; dst = d2; break;
        case 3: src = s3; dst = d3; break;
        case 4: src = s4; dst = d4; break;
        case 5: src = s5; dst = d5; break;
        default: src = s6; dst = d6; F = 64; break;
    }
    int t = blockIdx.x * 256 + threadIdx.x;
    if (t >= F * 128) return;
    int f = t >> 7, k = t & 127;
    dst[t] = f2bf(src[(size_t)k * F + f]);
}

// ---------------------------------------------------------------------------
// Graph preprocessing
// ---------------------------------------------------------------------------
__global__ void cnt_kernel(const int* __restrict__ ei, int* __restrict__ cnt, int E) {
    int e = (blockIdx.x * 256 + threadIdx.x) * 2;
    if (e + 1 < E) {
        int2 d = *(const int2*)(ei + E + e);
        atomicAdd(&cnt[d.x], 1);
        atomicAdd(&cnt[d.y], 1);
    } else if (e < E) {
        atomicAdd(&cnt[ei[E + e]], 1);
    }
}

// 3-phase scan: per-block exclusive scan + block sums; dinv fused in.
__device__ __forceinline__ void block_scan256(int v, int* lsum, int& excl, int& total) {
    int lane = threadIdx.x & 63, w = threadIdx.x >> 6;
    int inc = v;
    #pragma unroll
    for (int s = 1; s < 64; s <<= 1) {
        int t = __shfl_up(inc, s);
        if (lane >= s) inc += t;
    }
    if (lane == 63) lsum[w] = inc;
    __syncthreads();
    int pre = 0;
    #pragma unroll
    for (int k = 0; k < 4; ++k)
        if (k < w) pre += lsum[k];
    excl = pre + inc - v;
    total = lsum[0] + lsum[1] + lsum[2] + lsum[3];
    __syncthreads();
}

__global__ void scan_part_kernel(const int* __restrict__ cnt, int* __restrict__ part,
                                 int* __restrict__ bsum, float* __restrict__ dinv, int n) {
    __shared__ int lsum[4];
    int i = blockIdx.x * 256 + threadIdx.x;
    int v = (i < n) ? cnt[i] : 0;
    int excl, total;
    block_scan256(v, lsum, excl, total);
    if (i < n) {
        part[i] = excl;
        dinv[i] = rsqrtf((float)(v + 1));
    }
    if (threadIdx.x == 0) bsum[blockIdx.x] = total;
}

__global__ void scan_bsum_kernel(int* __restrict__ bsum, int nb) {
    __shared__ int lsum[4];
    int t = threadIdx.x;
    int v = (t < nb) ? bsum[t] : 0;
    int excl, total;
    block_scan256(v, lsum, excl, total);
    if (t < nb) bsum[t] = excl;
}

__global__ void scan_add_kernel(const int* __restrict__ part, const int* __restrict__ bsum,
                                int* __restrict__ off, int n) {
    int i = blockIdx.x * 256 + threadIdx.x;
    if (i < n) off[i] = part[i] + bsum[blockIdx.x];
    if (i == 0) off[n] = EE;
}

// Scatter edges into CSR by destination; packed {src, w_bits} -> one 8B write.
__global__ void fill_kernel(const int* __restrict__ ei, const int* __restrict__ off,
                            int* __restrict__ cursor, int2* __restrict__ csr,
                            const float* __restrict__ dinv, int E) {
    int e = blockIdx.x * 256 + threadIdx.x;
    if (e < E) {
        int s = ei[e];
        int d = ei[E + e];
        int pos = off[d] + atomicAdd(&cursor[d], 1);
        float w = dinv[s] * dinv[d];
        csr[pos] = make_int2(s, __builtin_bit_cast(int, w));
    }
}

// ---------------------------------------------------------------------------
// MFMA GEMM: Y[n,FOUT] = act(X[n,128] @ W[128,FOUT] + bias)
// X: bf16 row-major [n][128]; Wt: bf16 [FOUT][128] (pre-transposed, k contig).
// Block: 128 rows x FOUT cols, 4 waves (each 32 rows). K=128 LDS-resident.
// LDS 16B-chunk layout with XOR swizzle (kb ^= row&15) -> 2-way (free) reads.
// BNF: fold BatchNorm(scale,shift)+ReLU into X staging.
// ---------------------------------------------------------------------------
template <int FOUT, bool RELU, bool BIAS, bool BNF, bool OUTF32>
__global__ __launch_bounds__(256, 2) void gemm_mfma(
    const ushort* __restrict__ Xg, const ushort* __restrict__ Wt,
    const float* __restrict__ bias, const float* __restrict__ scale,
    const float* __restrict__ shift, void* __restrict__ Yout, int n) {
    constexpr int NCG = FOUT / 16;
    __shared__ uint4 lds4[2048 + FOUT * 16];
    uint4* Wl = lds4 + 2048;
    const int tid = threadIdx.x;
    const int row0 = blockIdx.x * 128;

    // stage W (bf16, pre-transposed: coalesced 16B chunks)
    #pragma unroll
    for (int c = tid; c < FOUT * 16; c += 256) {
        int f = c >> 4, kb = c & 15;
        uint4 v = ((const uint4*)Wt)[c];
        Wl[f * 16 + (kb ^ (f & 15))] = v;
    }
    // stage X (optionally with BN+ReLU fold)
    for (int c = tid; c < 2048; c += 256) {
        int r = c >> 4, kb = c & 15;
        int row = row0 + r;
        uint4 v = make_uint4(0, 0, 0, 0);
        if (row < n) v = ((const uint4*)(Xg + (size_t)row * 128))[kb];
        if (BNF) {
            uint a[4] = {v.x, v.y, v.z, v.w};
            #pragma unroll
            for (int p = 0; p < 4; ++p) {
                int f0 = kb * 8 + p * 2;
                float lo = bf2f_lo(a[p]);
                float hi = bf2f_hi(a[p]);
                lo = fmaxf(fmaf(lo, scale[f0], shift[f0]), 0.f);
                hi = fmaxf(fmaf(hi, scale[f0 + 1], shift[f0 + 1]), 0.f);
                a[p] = (uint)f2bf(lo) | ((uint)f2bf(hi) << 16);
            }
            v = make_uint4(a[0], a[1], a[2], a[3]);
        }
        lds4[r * 16 + (kb ^ (r & 15))] = v;
    }
    __syncthreads();

    const int wv = tid >> 6, lane = tid & 63;
    const int lr = lane & 15, lk = lane >> 4;

    floatx4 acc[2][NCG];
    #pragma unroll
    for (int rg = 0; rg < 2; ++rg)
        #pragma unroll
        for (int cg = 0; cg < NCG; ++cg)
            acc[rg][cg] = (floatx4){0.f, 0.f, 0.f, 0.f};

    #pragma unroll
    for (int ks = 0; ks < 4; ++ks) {
        int kb = ks * 4 + lk;          // this lane's 16B chunk along K
        int swz = kb ^ lr;             // same swizzle for A (row&15=lr) and B (f&15=lr)
        short8 a0 = *(const short8*)&lds4[(wv * 32 + lr) * 16 + swz];
        short8 a1 = *(const short8*)&lds4[(wv * 32 + 16 + lr) * 16 + swz];
        #pragma unroll
        for (int cg = 0; cg < NCG; ++cg) {
            short8 b = *(const short8*)&Wl[(cg * 16 + lr) * 16 + swz];
            acc[0][cg] = __builtin_amdgcn_mfma_f32_16x16x32_bf16(a0, b, acc[0][cg], 0, 0, 0);
            acc[1][cg] = __builtin_amdgcn_mfma_f32_16x16x32_bf16(a1, b, acc[1][cg], 0, 0, 0);
        }
    }

    // epilogue: D mapping col=lane&15, row=(lane>>4)*4+j
    #pragma unroll
    for (int rg = 0; rg < 2; ++rg) {
        int rbase = row0 + wv * 32 + rg * 16 + lk * 4;
        #pragma unroll
        for (int cg = 0; cg < NCG; ++cg) {
            int col = cg * 16 + lr;
            float bv = BIAS ? bias[col] : 0.f;
            #pragma unroll
            for (int j = 0; j < 4; ++j) {
                int r = rbase + j;
                if (r < n) {
                    float o = acc[rg][cg][j] + bv;
                    if (RELU) o = fmaxf(o, 0.f);
                    if (OUTF32)
                        ((float*)Yout)[(size_t)r * FOUT + col] = o;
                    else
                        ((ushort*)Yout)[(size_t)r * FOUT + col] = f2bf(o);
                }
            }
        }
    }
}

// ---------------------------------------------------------------------------
// Aggregation (bf16 rows): out[i] = sum_e h[src_e]*w_e + h[i]*dinv^2 + bias
// One wave per node; lane owns 2 features (one dword of 2 bf16). f32 accum.
// Edge stream is packed int2 {src, w_bits}; unrolled x4 for MLP.
// ---------------------------------------------------------------------------
__global__ __launch_bounds__(256) void agg16_kernel(const ushort* __restrict__ h,
                                                    const float* __restrict__ dinv,
                                                    const int* __restrict__ off,
                                                    const int2* __restrict__ csr,
                                                    const float* __restrict__ bias,
                                                    ushort* __restrict__ out, int n) {
    int i = (blockIdx.x * 256 + threadIdx.x) >> 6;
    if (i >= n) return;
    int lane = threadIdx.x & 63;

    float di = dinv[i];
    float sw = di * di;
    uint u = ((const uint*)(h + (size_t)i * 128))[lane];
    float a0 = bf2f_lo(u) * sw, a1 = bf2f_hi(u) * sw;

    const int s0 = off[i], s1 = off[i + 1];
    int j = s0;
    for (; j + 4 <= s1; j += 4) {
        int2 ea = csr[j + 0], eb = csr[j + 1];
        int2 ec = csr[j + 2], ed = csr[j + 3];
        float wa = __builtin_bit_cast(float, ea.y), wb = __builtin_bit_cast(float, eb.y);
        float wc = __builtin_bit_cast(float, ec.y), wd = __builtin_bit_cast(float, ed.y);
        uint ua = ((const uint*)(h + (size_t)ea.x * 128))[lane];
        uint ub = ((const uint*)(h + (size_t)eb.x * 128))[lane];
        uint uc = ((const uint*)(h + (size_t)ec.x * 128))[lane];
        uint ud = ((const uint*)(h + (size_t)ed.x * 128))[lane];
        a0 += bf2f_lo(ua) * wa + bf2f_lo(ub) * wb + bf2f_lo(uc) * wc + bf2f_lo(ud) * wd;
        a1 += bf2f_hi(ua) * wa + bf2f_hi(ub) * wb + bf2f_hi(uc) * wc + bf2f_hi(ud) * wd;
    }
    for (; j < s1; ++j) {
        int2 e = csr[j];
        float w = __builtin_bit_cast(float, e.y);
        uint uv = ((const uint*)(h + (size_t)e.x * 128))[lane];
        a0 += bf2f_lo(uv) * w;
        a1 += bf2f_hi(uv) * w;
    }

    float2 b2 = ((const float2*)bias)[lane];
    a0 += b2.x; a1 += b2.y;
    uint o = (uint)f2bf(a0) | ((uint)f2bf(a1) << 16);
    ((uint*)(out + (size_t)i * 128))[lane] = o;
}

// ---------------------------------------------------------------------------
// BatchNorm: stats on bf16 rows, then per-feature scale/shift coefficients
// ---------------------------------------------------------------------------
__global__ __launch_bounds__(256) void bn_stats16_kernel(const ushort* __restrict__ x,
                                                         float* __restrict__ sums,
                                                         float* __restrict__ sumsq, int n) {
    int f = threadIdx.x & 127;
    int half = threadIdx.x >> 7;
    float s = 0.f, q = 0.f;
    for (int r = blockIdx.x * 2 + half; r < n; r += gridDim.x * 2) {
        float v = bf2f(x[(size_t)r * 128 + f]);
        s += v;
        q += v * v;
    }
    atomicAdd(&sums[f], s);
    atomicAdd(&sumsq[f], q);
}

__global__ void bn_coef_kernel(const float* __restrict__ sums, const float* __restrict__ sumsq,
                               const float* __restrict__ g, const float* __restrict__ b,
                               float* __restrict__ scale, float* __restrict__ shift) {
    int f = threadIdx.x;
    if (f >= 128) return;
    const float inv_n = 1.0f / (float)NN;
    float m = sums[f] * inv_n;
    float var = sumsq[f] * inv_n - m * m;
    float sc = g[f] * rsqrtf(var + BN_EPS);
    scale[f] = sc;
    shift[f] = b[f] - m * sc;
}

// ---------------------------------------------------------------------------
extern "C" void kernel_launch(void* const* d_in, const int* in_sizes, int n_in,
                              void* d_out, int out_size, void* d_ws, size_t ws_size,
                              hipStream_t stream) {
    const float* x        = (const float*)d_in[0];
    const int*   ei       = (const int*)d_in[1];
    const float* pre_w1   = (const float*)d_in[2];
    const float* pre_b1   = (const float*)d_in[3];
    const float* pre_w2   = (const float*)d_in[4];
    const float* pre_b2   = (const float*)d_in[5];
    const float* conv_w0  = (const float*)d_in[6];
    const float* conv_b0  = (const float*)d_in[7];
    const float* conv_w1  = (const float*)d_in[8];
    const float* conv_b1  = (const float*)d_in[9];
    const float* conv_w2  = (const float*)d_in[10];
    const float* conv_b2  = (const float*)d_in[11];
    const float* bn_g0    = (const float*)d_in[12];
    const float* bn_b0    = (const float*)d_in[13];
    const float* bn_g1    = (const float*)d_in[14];
    const float* bn_b1    = (const float*)d_in[15];
    const float* post_w1  = (const float*)d_in[16];
    const float* post_b1  = (const float*)d_in[17];
    const float* post_w2  = (const float*)d_in[18];
    const float* post_b2  = (const float*)d_in[19];
    float* out = (float*)d_out;

    const int n = NN, E = EE;
    const int NB = (n + 255) / 256;   // scan blocks (196)

    // Workspace layout  (cnt and cursor adjacent -> one memset)
    char* w = (char*)d_ws;
    int* cnt    = (int*)w;   w += align_up((size_t)2 * n * 4, 512);
    int* cursor = cnt + n;
    int* part   = (int*)w;   w += align_up((size_t)n * 4, 512);
    int* bsum   = (int*)w;   w += align_up(256 * 4, 512);
    int* off    = (int*)w;   w += align_up((size_t)(n + 1) * 4, 512);
    float* dinv = (float*)w; w += align_up((size_t)n * 4, 512);
    int2* csr   = (int2*)w;  w += align_up((size_t)E * 8, 512);
    float* bns0 = (float*)w;            // sums0, sumsq0, sums1, sumsq1
    float* bnq0 = bns0 + 128;
    float* bns1 = bns0 + 256;
    float* bnq1 = bns0 + 384;
    w += align_up(4 * 128 * 4, 512);
    float* sc0  = (float*)w;            // scale0, shift0, scale1, shift1
    float* sh0  = sc0 + 128;
    float* sc1  = sc0 + 256;
    float* sh1  = sc0 + 384;
    w += align_up(4 * 128 * 4, 512);
    // bf16 transposed weights
    ushort* wt_pre1  = (ushort*)w; w += align_up(128 * 128 * 2, 512);
    ushort* wt_pre2  = (ushort*)w; w += align_up(128 * 128 * 2, 512);
    ushort* wt_c0    = (ushort*)w; w += align_up(128 * 128 * 2, 512);
    ushort* wt_c1    = (ushort*)w; w += align_up(128 * 128 * 2, 512);
    ushort* wt_c2    = (ushort*)w; w += align_up(128 * 128 * 2, 512);
    ushort* wt_post1 = (ushort*)w; w += align_up(128 * 128 * 2, 512);
    ushort* wt_post2 = (ushort*)w; w += align_up(64 * 128 * 2, 512);
    // bf16 activation buffers
    ushort* P = (ushort*)w; w += align_up((size_t)n * 128 * 2, 512);
    ushort* Q = (ushort*)w; w += align_up((size_t)n * 128 * 2, 512);
    ushort* R = (ushort*)w; w += align_up((size_t)n * 128 * 2, 512);

    hipMemsetAsync(cnt, 0, (size_t)2 * n * 4, stream);
    hipMemsetAsync(bns0, 0, 4 * 128 * 4, stream);

    // Casts
    castx_kernel<<<(n * 32 + 255) / 256, 256, 0, stream>>>(x, P, n * 32);
    tcast_all_kernel<<<dim3(64, 7), 256, 0, stream>>>(
        pre_w1, pre_w2, conv_w0, conv_w1, conv_w2, post_w1, post_w2,
        wt_pre1, wt_pre2, wt_c0, wt_c1, wt_c2, wt_post1, wt_post2);

    // Graph preprocessing
    cnt_kernel<<<(E / 2 + 255) / 256, 256, 0, stream>>>(ei, cnt, E);
    scan_part_kernel<<<NB, 256, 0, stream>>>(cnt, part, bsum, dinv, n);
    scan_bsum_kernel<<<1, 256, 0, stream>>>(bsum, NB);
    scan_add_kernel<<<NB, 256, 0, stream>>>(part, bsum, off, n);
    fill_kernel<<<(E + 255) / 256, 256, 0, stream>>>(ei, off, cursor, csr, dinv, E);

    const int gb = (n + 127) / 128;
    const int agg_blocks = (n * 64 + 255) / 256;

    // pre-proc MLP
    gemm_mfma<128, true, true, false, false><<<gb, 256, 0, stream>>>(P, wt_pre1, pre_b1, nullptr, nullptr, Q, n);
    gemm_mfma<128, true, true, false, false><<<gb, 256, 0, stream>>>(Q, wt_pre2, pre_b2, nullptr, nullptr, R, n);

    // conv0 -> agg -> BN0 stats/coefs (BN+ReLU folded into conv1 staging)
    gemm_mfma<128, false, false, false, false><<<gb, 256, 0, stream>>>(R, wt_c0, nullptr, nullptr, nullptr, P, n);
    agg16_kernel<<<agg_blocks, 256, 0, stream>>>(P, dinv, off, csr, conv_b0, Q, n);
    bn_stats16_kernel<<<512, 256, 0, stream>>>(Q, bns0, bnq0, n);
    bn_coef_kernel<<<1, 128, 0, stream>>>(bns0, bnq0, bn_g0, bn_b0, sc0, sh0);

    // conv1 (BN0 fold) -> agg -> BN1 stats/coefs
    gemm_mfma<128, false, false, true, false><<<gb, 256, 0, stream>>>(Q, wt_c1, nullptr, sc0, sh0, P, n);
    agg16_kernel<<<agg_blocks, 256, 0, stream>>>(P, dinv, off, csr, conv_b1, R, n);
    bn_stats16_kernel<<<512, 256, 0, stream>>>(R, bns1, bnq1, n);
    bn_coef_kernel<<<1, 128, 0, stream>>>(bns1, bnq1, bn_g1, bn_b1, sc1, sh1);

    // conv2 (BN1 fold) -> agg
    gemm_mfma<128, false, false, true, false><<<gb, 256, 0, stream>>>(R, wt_c2, nullptr, sc1, sh1, P, n);
    agg16_kernel<<<agg_blocks, 256, 0, stream>>>(P, dinv, off, csr, conv_b2, Q, n);

    // post-proc MLP
    gemm_mfma<128, true, true, false, false><<<gb, 256, 0, stream>>>(Q, wt_post1, post_b1, nullptr, nullptr, P, n);
    gemm_mfma<64, false, true, false, true><<<gb, 256, 0, stream>>>(P, wt_post2, post_b2, nullptr, nullptr, out, n);
}

// Round 5
// 408.811 us; speedup vs baseline: 2.2487x; 1.1982x over previous
//
#include <hip/hip_runtime.h>
#include <hip/hip_bf16.h>

// Problem constants (fixed by the reference setup)
#define NN 50000
#define EE 800000
#define DIN 128
#define HH 128
#define DOUT 64
#define BN_EPS 1e-5f

typedef __attribute__((ext_vector_type(8))) short short8;   // 8 bf16 (4 VGPRs)
typedef __attribute__((ext_vector_type(4))) float floatx4;  // MFMA acc

static inline size_t align_up(size_t x, size_t a) { return (x + a - 1) & ~(a - 1); }

// bf16 <-> f32 helpers (RNE round)
__device__ __forceinline__ float bf2f(ushort u) {
    uint v = ((uint)u) << 16;
    return __builtin_bit_cast(float, v);
}
__device__ __forceinline__ float bf2f_lo(uint u) { return __builtin_bit_cast(float, u << 16); }
__device__ __forceinline__ float bf2f_hi(uint u) { return __builtin_bit_cast(float, u & 0xffff0000u); }
__device__ __forceinline__ ushort f2bf(float f) {
    uint u = __builtin_bit_cast(uint, f);
    u += 0x7fff + ((u >> 16) & 1);
    return (ushort)(u >> 16);
}
__device__ __forceinline__ uint pack_bf2(float lo, float hi) {
    return (uint)f2bf(lo) | ((uint)f2bf(hi) << 16);
}

// ---------------------------------------------------------------------------
// All 7 weights in one dispatch: W[k][f] f32 -> Wt[f][k] bf16 (k contiguous)
// ---------------------------------------------------------------------------
__global__ void tcast_all_kernel(const float* __restrict__ s0, const float* __restrict__ s1,
                                 const float* __restrict__ s2, const float* __restrict__ s3,
                                 const float* __restrict__ s4, const float* __restrict__ s5,
                                 const float* __restrict__ s6,
                                 ushort* __restrict__ d0, ushort* __restrict__ d1,
                                 ushort* __restrict__ d2, ushort* __restrict__ d3,
                                 ushort* __restrict__ d4, ushort* __restrict__ d5,
                                 ushort* __restrict__ d6) {
    const float* src; ushort* dst; int F = 128;
    switch (blockIdx.y) {
        case 0: src = s0; dst = d0; break;
        case 1: src = s1; dst = d1; break;
        case 2: src = s2; dst = d2; break;
        case 3: src = s3; dst = d3; break;
        case 4: src = s4; dst = d4; break;
        case 5: src = s5; dst = d5; break;
        default: src = s6; dst = d6; F = 64; break;
    }
    int t = blockIdx.x * 256 + threadIdx.x;
    if (t >= F * 128) return;
    int f = t >> 7, k = t & 127;
    dst[t] = f2bf(src[(size_t)k * F + f]);
}

// ---------------------------------------------------------------------------
// Graph preprocessing
// ---------------------------------------------------------------------------
__global__ void cnt_kernel(const int* __restrict__ ei, int* __restrict__ cnt, int E) {
    int e = (blockIdx.x * 256 + threadIdx.x) * 4;
    if (e + 3 < E) {
        int4 d = *(const int4*)(ei + E + e);
        atomicAdd(&cnt[d.x], 1);
        atomicAdd(&cnt[d.y], 1);
        atomicAdd(&cnt[d.z], 1);
        atomicAdd(&cnt[d.w], 1);
    } else {
        for (; e < E; ++e) atomicAdd(&cnt[ei[E + e]], 1);
    }
}

__device__ __forceinline__ void block_scan256(int v, int* lsum, int& excl, int& total) {
    int lane = threadIdx.x & 63, w = threadIdx.x >> 6;
    int inc = v;
    #pragma unroll
    for (int s = 1; s < 64; s <<= 1) {
        int t = __shfl_up(inc, s);
        if (lane >= s) inc += t;
    }
    if (lane == 63) lsum[w] = inc;
    __syncthreads();
    int pre = 0;
    #pragma unroll
    for (int k = 0; k < 4; ++k)
        if (k < w) pre += lsum[k];
    excl = pre + inc - v;
    total = lsum[0] + lsum[1] + lsum[2] + lsum[3];
    __syncthreads();
}

// partial exclusive scan into off; block sums; dinv fused in
__global__ void scan_part_kernel(const int* __restrict__ cnt, int* __restrict__ off,
                                 int* __restrict__ bsum, float* __restrict__ dinv, int n) {
    __shared__ int lsum[4];
    int i = blockIdx.x * 256 + threadIdx.x;
    int v = (i < n) ? cnt[i] : 0;
    int excl, total;
    block_scan256(v, lsum, excl, total);
    if (i < n) {
        off[i] = excl;
        dinv[i] = rsqrtf((float)(v + 1));
    }
    if (threadIdx.x == 0) bsum[blockIdx.x] = total;
}

__global__ void scan_bsum_kernel(int* __restrict__ bsum, int nb) {
    __shared__ int lsum[4];
    int t = threadIdx.x;
    int v = (t < nb) ? bsum[t] : 0;
    int excl, total;
    block_scan256(v, lsum, excl, total);
    if (t < nb) bsum[t] = excl;
}

// finalize off and initialize cursor = off (fill then needs no off read)
__global__ void scan_add_kernel(int* __restrict__ off, const int* __restrict__ bsum,
                                int* __restrict__ cursor, int n) {
    int i = blockIdx.x * 256 + threadIdx.x;
    if (i < n) {
        int v = off[i] + bsum[blockIdx.x];
        off[i] = v;
        cursor[i] = v;
    }
    if (i == 0) off[n] = EE;
}

// Scatter edges into CSR by destination; packed {src, w_bits} -> one 8B write.
__global__ void fill_kernel(const int* __restrict__ ei, int* __restrict__ cursor,
                            int2* __restrict__ csr, const float* __restrict__ dinv, int E) {
    int e = blockIdx.x * 256 + threadIdx.x;
    if (e < E) {
        int s = ei[e];
        int d = ei[E + e];
        int pos = atomicAdd(&cursor[d], 1);
        float w = dinv[s] * dinv[d];
        csr[pos] = make_int2(s, __builtin_bit_cast(int, w));
    }
}

// ---------------------------------------------------------------------------
// Shared MFMA building blocks. LDS layout: [row/f][16 uint4-chunks] with
// chunk index XOR-swizzled by (row&15) -> ds_read_b128 is 2-way (free).
// ---------------------------------------------------------------------------
template <int NCG>
__device__ __forceinline__ void zero_acc(floatx4 (&acc)[2][NCG]) {
    #pragma unroll
    for (int rg = 0; rg < 2; ++rg)
        #pragma unroll
        for (int cg = 0; cg < NCG; ++cg)
            acc[rg][cg] = (floatx4){0.f, 0.f, 0.f, 0.f};
}

template <int FO>
__device__ __forceinline__ void stage_w(const ushort* __restrict__ Wt, uint4* Wl, int tid) {
    #pragma unroll
    for (int c = tid; c < FO * 16; c += 256) {
        int f = c >> 4, kb = c & 15;
        Wl[f * 16 + (kb ^ (f & 15))] = ((const uint4*)Wt)[c];
    }
}

template <int NCG>
__device__ __forceinline__ void gemm_step(const uint4* Xl, const uint4* Wl,
                                          floatx4 (&acc)[2][NCG], int wv, int lr, int lk) {
    #pragma unroll
    for (int ks = 0; ks < 4; ++ks) {
        int kb = ks * 4 + lk;
        int swz = kb ^ lr;
        short8 a0 = *(const short8*)&Xl[(wv * 32 + lr) * 16 + swz];
        short8 a1 = *(const short8*)&Xl[(wv * 32 + 16 + lr) * 16 + swz];
        #pragma unroll
        for (int cg = 0; cg < NCG; ++cg) {
            short8 b = *(const short8*)&Wl[(cg * 16 + lr) * 16 + swz];
            acc[0][cg] = __builtin_amdgcn_mfma_f32_16x16x32_bf16(a0, b, acc[0][cg], 0, 0, 0);
            acc[1][cg] = __builtin_amdgcn_mfma_f32_16x16x32_bf16(a1, b, acc[1][cg], 0, 0, 0);
        }
    }
}

// write H = relu(acc + bias) back into the X LDS buffer (bf16, same swizzle)
template <int NCG>
__device__ __forceinline__ void write_h(floatx4 (&acc)[2][NCG], uint4* Xl,
                                        const float* __restrict__ bias,
                                        int wv, int lr, int lk) {
    ushort* Xs = (ushort*)Xl;
    #pragma unroll
    for (int rg = 0; rg < 2; ++rg)
        #pragma unroll
        for (int cg = 0; cg < NCG; ++cg) {
            int col = cg * 16 + lr;
            float bv = bias[col];
            #pragma unroll
            for (int j = 0; j < 4; ++j) {
                int row = wv * 32 + rg * 16 + lk * 4 + j;
                float o = fmaxf(acc[rg][cg][j] + bv, 0.f);
                Xs[(row * 16 + ((col >> 3) ^ (row & 15))) * 8 + (col & 7)] = f2bf(o);
            }
        }
}

template <int FOUT, bool RELU, bool BIAS, bool OUTF32>
__device__ __forceinline__ void epilogue(floatx4 (&acc)[2][FOUT / 16],
                                         const float* __restrict__ bias, void* Yout,
                                         int row0, int n, int wv, int lr, int lk) {
    #pragma unroll
    for (int rg = 0; rg < 2; ++rg) {
        int rbase = row0 + wv * 32 + rg * 16 + lk * 4;
        #pragma unroll
        for (int cg = 0; cg < FOUT / 16; ++cg) {
            int col = cg * 16 + lr;
            float bv = BIAS ? bias[col] : 0.f;
            #pragma unroll
            for (int j = 0; j < 4; ++j) {
                int r = rbase + j;
                if (r < n) {
                    float o = acc[rg][cg][j] + bv;
                    if (RELU) o = fmaxf(o, 0.f);
                    if (OUTF32)
                        ((float*)Yout)[(size_t)r * FOUT + col] = o;
                    else
                        ((ushort*)Yout)[(size_t)r * FOUT + col] = f2bf(o);
                }
            }
        }
    }
}

// ---------------------------------------------------------------------------
// Fused pre-MLP + conv0 GEMM: P = relu(relu(X@W1+b1)@W2+b2)@W0c
// X is f32 (cast during staging). 3 GEMMs, H kept in LDS. 64KB LDS, 2 blk/CU.
// ---------------------------------------------------------------------------
__global__ __launch_bounds__(256, 2) void fused_pre_kernel(
    const float* __restrict__ Xg, const ushort* __restrict__ W1t, const float* __restrict__ b1,
    const ushort* __restrict__ W2t, const float* __restrict__ b2,
    const ushort* __restrict__ W3t, ushort* __restrict__ Yout, int n) {
    __shared__ uint4 lds4[4096];
    uint4* Xl = lds4;
    uint4* Wl = lds4 + 2048;
    const int tid = threadIdx.x;
    const int row0 = blockIdx.x * 128;

    // stage X with f32->bf16 cast
    for (int c = tid; c < 2048; c += 256) {
        int r = c >> 4, kb = c & 15;
        int row = row0 + r;
        uint4 v = make_uint4(0, 0, 0, 0);
        if (row < n) {
            const float4* p = (const float4*)(Xg + (size_t)row * 128 + kb * 8);
            float4 x0 = p[0], x1 = p[1];
            v.x = pack_bf2(x0.x, x0.y);
            v.y = pack_bf2(x0.z, x0.w);
            v.z = pack_bf2(x1.x, x1.y);
            v.w = pack_bf2(x1.z, x1.w);
        }
        Xl[r * 16 + (kb ^ (r & 15))] = v;
    }
    stage_w<128>(W1t, Wl, tid);
    __syncthreads();

    const int wv = tid >> 6, lane = tid & 63;
    const int lr = lane & 15, lk = lane >> 4;

    floatx4 acc[2][8];
    zero_acc<8>(acc);
    gemm_step<8>(Xl, Wl, acc, wv, lr, lk);
    __syncthreads();
    write_h<8>(acc, Xl, b1, wv, lr, lk);
    stage_w<128>(W2t, Wl, tid);
    __syncthreads();

    zero_acc<8>(acc);
    gemm_step<8>(Xl, Wl, acc, wv, lr, lk);
    __syncthreads();
    write_h<8>(acc, Xl, b2, wv, lr, lk);
    stage_w<128>(W3t, Wl, tid);
    __syncthreads();

    zero_acc<8>(acc);
    gemm_step<8>(Xl, Wl, acc, wv, lr, lk);
    epilogue<128, false, false, false>(acc, nullptr, Yout, row0, n, wv, lr, lk);
}

// ---------------------------------------------------------------------------
// Fused post-MLP: out = relu(X@W1+b1)@W2 + b2   (f32 output, DOUT=64)
// ---------------------------------------------------------------------------
__global__ __launch_bounds__(256, 2) void fused_post_kernel(
    const ushort* __restrict__ Xg, const ushort* __restrict__ W1t, const float* __restrict__ b1,
    const ushort* __restrict__ W2t, const float* __restrict__ b2,
    float* __restrict__ Yout, int n) {
    __shared__ uint4 lds4[4096];
    uint4* Xl = lds4;
    uint4* Wl = lds4 + 2048;
    const int tid = threadIdx.x;
    const int row0 = blockIdx.x * 128;

    for (int c = tid; c < 2048; c += 256) {
        int r = c >> 4, kb = c & 15;
        int row = row0 + r;
        uint4 v = make_uint4(0, 0, 0, 0);
        if (row < n) v = ((const uint4*)(Xg + (size_t)row * 128))[kb];
        Xl[r * 16 + (kb ^ (r & 15))] = v;
    }
    stage_w<128>(W1t, Wl, tid);
    __syncthreads();

    const int wv = tid >> 6, lane = tid & 63;
    const int lr = lane & 15, lk = lane >> 4;

    floatx4 acc[2][8];
    zero_acc<8>(acc);
    gemm_step<8>(Xl, Wl, acc, wv, lr, lk);
    __syncthreads();
    write_h<8>(acc, Xl, b1, wv, lr, lk);
    stage_w<64>(W2t, Wl, tid);
    __syncthreads();

    floatx4 acc2[2][4];
    zero_acc<4>(acc2);
    gemm_step<4>(Xl, Wl, acc2, wv, lr, lk);
    epilogue<64, false, true, true>(acc2, b2, Yout, row0, n, wv, lr, lk);
}

// ---------------------------------------------------------------------------
// Single GEMM with BatchNorm+ReLU folded into X staging; coefs computed
// in-kernel from raw sums/sumsq (saves the bn_coef dispatch).
// ---------------------------------------------------------------------------
__global__ __launch_bounds__(256, 2) void gemm_bnf_kernel(
    const ushort* __restrict__ Xg, const ushort* __restrict__ Wt,
    const float* __restrict__ sums, const float* __restrict__ sumsq,
    const float* __restrict__ g, const float* __restrict__ bb,
    ushort* __restrict__ Yout, int n) {
    __shared__ uint4 lds4[4096];
    __shared__ float scf[128], shf[128];
    uint4* Xl = lds4;
    uint4* Wl = lds4 + 2048;
    const int tid = threadIdx.x;
    const int row0 = blockIdx.x * 128;

    if (tid < 128) {
        const float inv_n = 1.0f / (float)NN;
        float m = sums[tid] * inv_n;
        float var = sumsq[tid] * inv_n - m * m;
        float sc = g[tid] * rsqrtf(var + BN_EPS);
        scf[tid] = sc;
        shf[tid] = bb[tid] - m * sc;
    }
    stage_w<128>(Wt, Wl, tid);
    __syncthreads();

    for (int c = tid; c < 2048; c += 256) {
        int r = c >> 4, kb = c & 15;
        int row = row0 + r;
        uint4 v = make_uint4(0, 0, 0, 0);
        if (row < n) v = ((const uint4*)(Xg + (size_t)row * 128))[kb];
        uint a[4] = {v.x, v.y, v.z, v.w};
        #pragma unroll
        for (int p = 0; p < 4; ++p) {
            int f0 = kb * 8 + p * 2;
            float lo = fmaxf(fmaf(bf2f_lo(a[p]), scf[f0], shf[f0]), 0.f);
            float hi = fmaxf(fmaf(bf2f_hi(a[p]), scf[f0 + 1], shf[f0 + 1]), 0.f);
            a[p] = pack_bf2(lo, hi);
        }
        Xl[r * 16 + (kb ^ (r & 15))] = make_uint4(a[0], a[1], a[2], a[3]);
    }
    __syncthreads();

    const int wv = tid >> 6, lane = tid & 63;
    const int lr = lane & 15, lk = lane >> 4;

    floatx4 acc[2][8];
    zero_acc<8>(acc);
    gemm_step<8>(Xl, Wl, acc, wv, lr, lk);
    epilogue<128, false, false, false>(acc, nullptr, Yout, row0, n, wv, lr, lk);
}

// ---------------------------------------------------------------------------
// Aggregation (bf16 rows): out[i] = sum_e h[src_e]*w_e + h[i]*dinv^2 + bias
// One wave per node; lane owns 2 features. f32 accum; packed int2 edges.
// ---------------------------------------------------------------------------
__global__ __launch_bounds__(256) void agg16_kernel(const ushort* __restrict__ h,
                                                    const float* __restrict__ dinv,
                                                    const int* __restrict__ off,
                                                    const int2* __restrict__ csr,
                                                    const float* __restrict__ bias,
                                                    ushort* __restrict__ out, int n) {
    int i = (blockIdx.x * 256 + threadIdx.x) >> 6;
    if (i >= n) return;
    int lane = threadIdx.x & 63;

    float di = dinv[i];
    float sw = di * di;
    uint u = ((const uint*)(h + (size_t)i * 128))[lane];
    float a0 = bf2f_lo(u) * sw, a1 = bf2f_hi(u) * sw;

    const int s0 = off[i], s1 = off[i + 1];
    int j = s0;
    for (; j + 4 <= s1; j += 4) {
        int2 ea = csr[j + 0], eb = csr[j + 1];
        int2 ec = csr[j + 2], ed = csr[j + 3];
        float wa = __builtin_bit_cast(float, ea.y), wb = __builtin_bit_cast(float, eb.y);
        float wc = __builtin_bit_cast(float, ec.y), wd = __builtin_bit_cast(float, ed.y);
        uint ua = ((const uint*)(h + (size_t)ea.x * 128))[lane];
        uint ub = ((const uint*)(h + (size_t)eb.x * 128))[lane];
        uint uc = ((const uint*)(h + (size_t)ec.x * 128))[lane];
        uint ud = ((const uint*)(h + (size_t)ed.x * 128))[lane];
        a0 += bf2f_lo(ua) * wa + bf2f_lo(ub) * wb + bf2f_lo(uc) * wc + bf2f_lo(ud) * wd;
        a1 += bf2f_hi(ua) * wa + bf2f_hi(ub) * wb + bf2f_hi(uc) * wc + bf2f_hi(ud) * wd;
    }
    for (; j < s1; ++j) {
        int2 e = csr[j];
        float w = __builtin_bit_cast(float, e.y);
        uint uv = ((const uint*)(h + (size_t)e.x * 128))[lane];
        a0 += bf2f_lo(uv) * w;
        a1 += bf2f_hi(uv) * w;
    }

    float2 b2 = ((const float2*)bias)[lane];
    a0 += b2.x; a1 += b2.y;
    ((uint*)(out + (size_t)i * 128))[lane] = pack_bf2(a0, a1);
}

// ---------------------------------------------------------------------------
// BatchNorm statistics: vectorized uint4 (8 bf16) loads, LDS reduce, atomics.
// ---------------------------------------------------------------------------
__global__ __launch_bounds__(256) void bn_stats16_kernel(const ushort* __restrict__ x,
                                                         float* __restrict__ sums,
                                                         float* __restrict__ sumsq, int n) {
    __shared__ float ls[128], lq[128];
    int tid = threadIdx.x;
    if (tid < 128) { ls[tid] = 0.f; lq[tid] = 0.f; }
    __syncthreads();
    int fg = tid & 15, rg = tid >> 4;
    float s[8] = {}, q[8] = {};
    for (int r = blockIdx.x * 16 + rg; r < n; r += gridDim.x * 16) {
        uint4 v = ((const uint4*)(x + (size_t)r * 128))[fg];
        uint a[4] = {v.x, v.y, v.z, v.w};
        #pragma unroll
        for (int p = 0; p < 4; ++p) {
            float lo = bf2f_lo(a[p]), hi = bf2f_hi(a[p]);
            s[2 * p] += lo;     q[2 * p] += lo * lo;
            s[2 * p + 1] += hi; q[2 * p + 1] += hi * hi;
        }
    }
    #pragma unroll
    for (int k = 0; k < 8; ++k) {
        atomicAdd(&ls[fg * 8 + k], s[k]);
        atomicAdd(&lq[fg * 8 + k], q[k]);
    }
    __syncthreads();
    if (tid < 128) {
        atomicAdd(&sums[tid], ls[tid]);
        atomicAdd(&sumsq[tid], lq[tid]);
    }
}

// ---------------------------------------------------------------------------
extern "C" void kernel_launch(void* const* d_in, const int* in_sizes, int n_in,
                              void* d_out, int out_size, void* d_ws, size_t ws_size,
                              hipStream_t stream) {
    const float* x        = (const float*)d_in[0];
    const int*   ei       = (const int*)d_in[1];
    const float* pre_w1   = (const float*)d_in[2];
    const float* pre_b1   = (const float*)d_in[3];
    const float* pre_w2   = (const float*)d_in[4];
    const float* pre_b2   = (const float*)d_in[5];
    const float* conv_w0  = (const float*)d_in[6];
    const float* conv_b0  = (const float*)d_in[7];
    const float* conv_w1  = (const float*)d_in[8];
    const float* conv_b1  = (const float*)d_in[9];
    const float* conv_w2  = (const float*)d_in[10];
    const float* conv_b2  = (const float*)d_in[11];
    const float* bn_g0    = (const float*)d_in[12];
    const float* bn_b0    = (const float*)d_in[13];
    const float* bn_g1    = (const float*)d_in[14];
    const float* bn_b1    = (const float*)d_in[15];
    const float* post_w1  = (const float*)d_in[16];
    const float* post_b1  = (const float*)d_in[17];
    const float* post_w2  = (const float*)d_in[18];
    const float* post_b2  = (const float*)d_in[19];
    float* out = (float*)d_out;

    const int n = NN, E = EE;
    const int NB = (n + 255) / 256;

    // Workspace layout (cnt followed by BN sums region -> single memset)
    char* w = (char*)d_ws;
    int* cnt    = (int*)w;   w += (size_t)n * 4;          // n*4 = 200000, 16B-aligned
    float* bns0 = (float*)w; // sums0, sumsq0, sums1, sumsq1 (512 floats)
    float* bnq0 = bns0 + 128;
    float* bns1 = bns0 + 256;
    float* bnq1 = bns0 + 384;
    w += align_up(512 * 4, 512);
    int* cursor = (int*)w;   w += align_up((size_t)n * 4, 512);
    int* bsum   = (int*)w;   w += align_up(256 * 4, 512);
    int* off    = (int*)w;   w += align_up((size_t)(n + 1) * 4, 512);
    float* dinv = (float*)w; w += align_up((size_t)n * 4, 512);
    int2* csr   = (int2*)w;  w += align_up((size_t)E * 8, 512);
    ushort* wt_pre1  = (ushort*)w; w += align_up(128 * 128 * 2, 512);
    ushort* wt_pre2  = (ushort*)w; w += align_up(128 * 128 * 2, 512);
    ushort* wt_c0    = (ushort*)w; w += align_up(128 * 128 * 2, 512);
    ushort* wt_c1    = (ushort*)w; w += align_up(128 * 128 * 2, 512);
    ushort* wt_c2    = (ushort*)w; w += align_up(128 * 128 * 2, 512);
    ushort* wt_post1 = (ushort*)w; w += align_up(128 * 128 * 2, 512);
    ushort* wt_post2 = (ushort*)w; w += align_up(64 * 128 * 2, 512);
    ushort* P = (ushort*)w; w += align_up((size_t)n * 128 * 2, 512);
    ushort* Q = (ushort*)w; w += align_up((size_t)n * 128 * 2, 512);
    ushort* R = (ushort*)w; w += align_up((size_t)n * 128 * 2, 512);

    hipMemsetAsync(cnt, 0, (size_t)n * 4 + 512 * 4, stream);

    // Weight transposes/casts (one dispatch)
    tcast_all_kernel<<<dim3(64, 7), 256, 0, stream>>>(
        pre_w1, pre_w2, conv_w0, conv_w1, conv_w2, post_w1, post_w2,
        wt_pre1, wt_pre2, wt_c0, wt_c1, wt_c2, wt_post1, wt_post2);

    // Graph preprocessing
    cnt_kernel<<<(E / 4 + 255) / 256, 256, 0, stream>>>(ei, cnt, E);
    scan_part_kernel<<<NB, 256, 0, stream>>>(cnt, off, bsum, dinv, n);
    scan_bsum_kernel<<<1, 256, 0, stream>>>(bsum, NB);
    scan_add_kernel<<<NB, 256, 0, stream>>>(off, bsum, cursor, n);
    fill_kernel<<<(E + 255) / 256, 256, 0, stream>>>(ei, cursor, csr, dinv, E);

    const int gb = (n + 127) / 128;
    const int agg_blocks = (n * 64 + 255) / 256;

    // pre-MLP + conv0 (fused)
    fused_pre_kernel<<<gb, 256, 0, stream>>>(x, wt_pre1, pre_b1, wt_pre2, pre_b2, wt_c0, P, n);
    agg16_kernel<<<agg_blocks, 256, 0, stream>>>(P, dinv, off, csr, conv_b0, Q, n);
    bn_stats16_kernel<<<256, 256, 0, stream>>>(Q, bns0, bnq0, n);

    // conv1 (BN0 fold, coef in-kernel)
    gemm_bnf_kernel<<<gb, 256, 0, stream>>>(Q, wt_c1, bns0, bnq0, bn_g0, bn_b0, P, n);
    agg16_kernel<<<agg_blocks, 256, 0, stream>>>(P, dinv, off, csr, conv_b1, R, n);
    bn_stats16_kernel<<<256, 256, 0, stream>>>(R, bns1, bnq1, n);

    // conv2 (BN1 fold)
    gemm_bnf_kernel<<<gb, 256, 0, stream>>>(R, wt_c2, bns1, bnq1, bn_g1, bn_b1, P, n);
    agg16_kernel<<<agg_blocks, 256, 0, stream>>>(P, dinv, off, csr, conv_b2, Q, n);

    // post-MLP (fused)
    fused_post_kernel<<<gb, 256, 0, stream>>>(Q, wt_post1, post_b1, wt_post2, post_b2, out, n);
}